// Round 3
// baseline (28923.184 us; speedup 1.0000x reference)
//
#include <hip/hip_runtime.h>
#include <hip/hip_bf16.h>

#define HDIM 1024
#define VDIM 512
#define TLEN 256
#define BATCH 256
#define FPDIM 2048
#define H3 3072
#define NBLK 216

typedef __hip_bfloat16 bf16;
typedef __attribute__((ext_vector_type(8))) short s8v;    // 8 bf16 (4 VGPRs)
typedef __attribute__((ext_vector_type(4))) float f4v;    // MFMA C/D

__device__ __forceinline__ f4v mfma_bf16(s8v a, s8v b, f4v c) {
  return __builtin_amdgcn_mfma_f32_16x16x32_bf16(a, b, c, 0, 0, 0);
}
__device__ __forceinline__ s8v ld8(const short* p) { return *(const s8v*)p; }
__device__ __forceinline__ float sigf(float x) { return 1.f / (1.f + expf(-x)); }
// fp32 -> bf16 bits, RNE
__device__ __forceinline__ short f2bs(float f) {
  union { float f; unsigned u; } c; c.f = f;
  unsigned u = c.u + 0x7fff + ((c.u >> 16) & 1);
  return (short)(u >> 16);
}

// ============ one-time: fp32 [N,1024] -> bf16 MFMA-frag blob ============
// blob[((nt*32+kc)*64 + lane)*8 + j]; n = nt*16+(lane&15), k = kc*32+(lane>>4)*8+j
__global__ __launch_bounds__(256) void shuffle_w(const float* __restrict__ src,
                                                 bf16* __restrict__ dst, int ngroups) {
  int g = blockIdx.x * 256 + threadIdx.x;
  if (g >= ngroups) return;
  int lane = g & 63, kc = (g >> 6) & 31, nt = g >> 11;
  int n = nt * 16 + (lane & 15);
  int k = kc * 32 + ((lane >> 4) << 3);
  const float* s = src + (size_t)n * HDIM + k;
  short* d = (short*)dst + (size_t)g * 8;
  s8v v;
#pragma unroll
  for (int j = 0; j < 8; ++j) v[j] = f2bs(s[j]);
  *(s8v*)d = v;
}

// ============ one-time fp32 tile GEMM: C = [relu](A[M,K] @ W[N,K]^T + bias [+bias2 if n<lim]) ============
struct GemmArgs {
  const float* A; const float* W; const float* bias; const float* bias2;
  float* C; int ldc; int K; int reluA; int reluC; int b2lim;
};
#define LDP 68
__global__ __launch_bounds__(256) void gemm_bt(GemmArgs g) {
  __shared__ float As[16][LDP];
  __shared__ float Ws[16][LDP];
  const int tid = threadIdx.x;
  const int tx = tid & 15, ty = tid >> 4;
  const int m0 = blockIdx.y * 64, n0 = blockIdx.x * 64;
  float acc[4][4] = {{0.f, 0.f, 0.f, 0.f}};
  const int K = g.K;
  for (int kb = 0; kb < K / 16; ++kb) {
    const int k0 = kb * 16;
#pragma unroll
    for (int i = 0; i < 4; ++i) {
      int idx = tid + i * 256;
      int ml = idx >> 4, kl = idx & 15;
      float a = g.A[(size_t)(m0 + ml) * K + k0 + kl];
      if (g.reluA) a = fmaxf(a, 0.f);
      As[kl][ml] = a;
      Ws[kl][ml] = g.W[(size_t)(n0 + ml) * K + k0 + kl];
    }
    __syncthreads();
#pragma unroll
    for (int k = 0; k < 16; ++k) {
      float4 av = *(const float4*)&As[k][ty * 4];
      float4 wv = *(const float4*)&Ws[k][tx * 4];
      float a[4] = {av.x, av.y, av.z, av.w};
      float w[4] = {wv.x, wv.y, wv.z, wv.w};
#pragma unroll
      for (int i = 0; i < 4; ++i)
#pragma unroll
        for (int j = 0; j < 4; ++j)
          acc[i][j] = fmaf(a[i], w[j], acc[i][j]);
    }
    __syncthreads();
  }
#pragma unroll
  for (int i = 0; i < 4; ++i) {
    int m = m0 + ty * 4 + i;
#pragma unroll
    for (int j = 0; j < 4; ++j) {
      int n = n0 + tx * 4 + j;
      float v = acc[i][j] + g.bias[n];
      if (g.bias2 && n < g.b2lim) v += g.bias2[n];
      if (g.reluC) v = fmaxf(v, 0.f);
      g.C[(size_t)m * g.ldc + n] = v;
    }
  }
}

// ============ one-time: duplicate init hidden into both layers' fp32 state bufs ============
__global__ __launch_bounds__(256) void copy2(const float* __restrict__ s,
                                             float* __restrict__ d0,
                                             float* __restrict__ d1) {
  int i = blockIdx.x * 256 + threadIdx.x;
  float v = s[i];
  d0[i] = v; d1[i] = v;
}

// init hidden -> frag blobs (both layers)
__global__ __launch_bounds__(256) void permute_frag(const float* __restrict__ s,
                                                    bf16* __restrict__ d0,
                                                    bf16* __restrict__ d1) {
  int g = blockIdx.x * 256 + threadIdx.x;      // (B/16)*32*64 groups
  int lane = g & 63, kc = (g >> 6) & 31, mt = g >> 11;
  int m = mt * 16 + (lane & 15), k = kc * 32 + ((lane >> 4) << 3);
  const float* src = s + (size_t)m * HDIM + k;
  s8v v;
#pragma unroll
  for (int j = 0; j < 8; ++j) v[j] = f2bs(src[j]);
  *(s8v*)((short*)d0 + (size_t)g * 8) = v;
  *(s8v*)((short*)d1 + (size_t)g * 8) = v;
}

// ============ persistent fused decoder ============
// ONE kernel for all 256 steps. 216 blocks x 512 thr, 1 block/CU (96 KB LDS).
// Roles: blk 0..63 L0 (16 hcols, Whh0 slice in LDS, BM=256)
//        blk 64..191 L1 (16 hcols, Wih1 slice in LDS, Whh1 streamed, BM=128)
//        blk 192..207 OPG (32 V-cols, Wo slice in LDS, BM=256, writes logits)
//        blk 208..215 OPS (log-softmax of 32 rows each)
// Pipeline at iter k: L0(t=k) | L1(t=k-1) | OPG(t=k-2) | OPS(t=k-3),
// separated by a device-scope grid barrier (cnt+gen in g.bar).
struct PArgs {
  const int* target;
  const float* table;          // [V,3H] fp32
  const float* bhh0n;          // b_hh0 + 2048
  const float* bih1; const float* bhh1; const float* bo;
  const bf16* Whh1;            // L1 h-src weight blob (streamed per step)
  bf16 *H0f0, *H0f1, *H1f0, *H1f1;
  float *H0l0, *H0l1, *H1l0, *H1l1;
  float *LG0, *LG1;            // logits double buffer [256][512] f32
  float* out;
  unsigned* bar;               // [0]=cnt [1]=gen
  const bf16 *Whh0, *Wih1, *Wof;   // blobs for LDS staging
};

__device__ __forceinline__ void gridbar(unsigned* bar, int tid) {
  __threadfence();             // release: drain + write-back this block's stores
  __syncthreads();
  if (tid == 0) {
    unsigned gen = __hip_atomic_load(bar + 1, __ATOMIC_RELAXED, __HIP_MEMORY_SCOPE_AGENT);
    unsigned a = __hip_atomic_fetch_add(bar, 1u, __ATOMIC_ACQ_REL, __HIP_MEMORY_SCOPE_AGENT);
    if (a == NBLK - 1) {
      __hip_atomic_store(bar, 0u, __ATOMIC_RELAXED, __HIP_MEMORY_SCOPE_AGENT);
      __hip_atomic_fetch_add(bar + 1, 1u, __ATOMIC_RELEASE, __HIP_MEMORY_SCOPE_AGENT);
    } else {
      while (__hip_atomic_load(bar + 1, __ATOMIC_RELAXED, __HIP_MEMORY_SCOPE_AGENT) == gen)
        __builtin_amdgcn_s_sleep(2);
    }
  }
  __syncthreads();
  __threadfence();             // acquire: invalidate so fresh cross-XCD state is visible
}

__global__ __launch_bounds__(512, 2) void step_persist(PArgs g) {
  extern __shared__ short lds[];               // 96 KB dynamic
  const int blk = blockIdx.x, tid = threadIdx.x;
  const int w = tid >> 6, ln = tid & 63, l15 = ln & 15, quad = ln >> 4;
  s8v* ls = (s8v*)lds;

  // ---- stage this block's static weight slice into LDS (once) ----
  if (blk < 64) {
    const int hg = blk;
#pragma unroll
    for (int gi = 0; gi < 3; ++gi) {
      const s8v* src = (const s8v*)((const short*)g.Whh0 + (size_t)(gi * 64 + hg) * 16384);
      for (int i = tid; i < 2048; i += 512) ls[gi * 2048 + i] = src[i];
    }
  } else if (blk < 192) {
    const int ng = (blk - 64) & 63;
#pragma unroll
    for (int gi = 0; gi < 3; ++gi) {
      const s8v* src = (const s8v*)((const short*)g.Wih1 + (size_t)(gi * 64 + ng) * 16384);
      for (int i = tid; i < 2048; i += 512) ls[gi * 2048 + i] = src[i];
    }
  } else if (blk < 208) {
    const int og = blk - 192;
#pragma unroll
    for (int u = 0; u < 2; ++u) {
      const s8v* src = (const s8v*)((const short*)g.Wof + (size_t)(og * 2 + u) * 16384);
      for (int i = tid; i < 2048; i += 512) ls[u * 2048 + i] = src[i];
    }
  }
  __syncthreads();

  const f4v z4 = {0.f, 0.f, 0.f, 0.f};

  if (blk < 64) {
    // ================= L0: t = k =================
    const int hg = blk;
    const int MT0 = w * 2;
    const int n = hg * 16 + l15;
    const float bhn = g.bhh0n[n];
    const int kc2 = hg >> 1;
    const int lhigh = ((hg & 1) << 1) + (l15 >> 3);
    const int jp = l15 & 7;
    const int aoff = MT0 * 16384 + ln * 8;
    for (int k = 0; k <= TLEN + 2; ++k) {
      if (k <= 255) {
        const short* h0f_in = (const short*)((k & 1) ? g.H0f1 : g.H0f0);
        short* h0f_out = (short*)((k & 1) ? g.H0f0 : g.H0f1);
        const float* h0l_in = (k & 1) ? g.H0l1 : g.H0l0;
        float* h0l_out = (k & 1) ? g.H0l0 : g.H0l1;
        float tr_[2][4], tz_[2][4], tn_[2][4], hp[2][4];
#pragma unroll
        for (int mi = 0; mi < 2; ++mi)
#pragma unroll
          for (int r = 0; r < 4; ++r) {
            const int m = ((MT0 + mi) << 4) + (quad << 2) + r;
            const int tok = k ? g.target[m * TLEN + k - 1] : 0;
            const float* trow = g.table + (size_t)tok * H3;
            tr_[mi][r] = trow[n];
            tz_[mi][r] = trow[n + 1024];
            tn_[mi][r] = trow[n + 2048];
            hp[mi][r] = h0l_in[(size_t)m * HDIM + n];
          }
        f4v a0[2] = {z4, z4}, a1[2] = {z4, z4}, a2[2] = {z4, z4};
        const short* pA = h0f_in + aoff;
#pragma unroll 4
        for (int kc = 0; kc < 32; ++kc) {
          s8v A0 = ld8(pA + kc * 512);
          s8v A1 = ld8(pA + 16384 + kc * 512);
          s8v B0 = ls[kc * 64 + ln];
          s8v B1 = ls[2048 + kc * 64 + ln];
          s8v B2 = ls[4096 + kc * 64 + ln];
          a0[0] = mfma_bf16(A0, B0, a0[0]); a0[1] = mfma_bf16(A1, B0, a0[1]);
          a1[0] = mfma_bf16(A0, B1, a1[0]); a1[1] = mfma_bf16(A1, B1, a1[1]);
          a2[0] = mfma_bf16(A0, B2, a2[0]); a2[1] = mfma_bf16(A1, B2, a2[1]);
        }
#pragma unroll
        for (int mi = 0; mi < 2; ++mi) {
          const int MT = MT0 + mi;
          short* fo = h0f_out + (((size_t)(MT * 32 + kc2)) << 9) + jp;
#pragma unroll
          for (int r = 0; r < 4; ++r) {
            const int m = (MT << 4) + (quad << 2) + r;
            float rr = sigf(tr_[mi][r] + a0[mi][r]);
            float zz = sigf(tz_[mi][r] + a1[mi][r]);
            float nn = tanhf(tn_[mi][r] + rr * (a2[mi][r] + bhn));
            float hv = (1.f - zz) * nn + zz * hp[mi][r];
            h0l_out[(size_t)m * HDIM + n] = hv;
            fo[((quad << 2) + r + (lhigh << 4)) * 8] = f2bs(hv);
          }
        }
      }
      if (k < TLEN + 2) gridbar(g.bar, tid);
    }
  } else if (blk < 192) {
    // ================= L1: t = k-1 =================
    const int b1 = blk - 64;
    const int ng = b1 & 63, mg = b1 >> 6;
    const int MT = mg * 8 + w;
    const int n = ng * 16 + l15;
    const float br = g.bih1[n] + g.bhh1[n];
    const float bz = g.bih1[n + 1024] + g.bhh1[n + 1024];
    const float bin = g.bih1[n + 2048], bhn = g.bhh1[n + 2048];
    const int kc2 = ng >> 1;
    const int lhigh = ((ng & 1) << 1) + (l15 >> 3);
    const int jp = l15 & 7;
    const int aoff = MT * 16384 + ln * 8;
    const short* pH0 = (const short*)g.Whh1 + (size_t)(ng) * 16384 + ln * 8;
    const short* pH1 = (const short*)g.Whh1 + (size_t)(64 + ng) * 16384 + ln * 8;
    const short* pH2 = (const short*)g.Whh1 + (size_t)(128 + ng) * 16384 + ln * 8;
    for (int k = 0; k <= TLEN + 2; ++k) {
      if (k >= 1 && k <= 256) {
        const short* h0f_in = (const short*)((k & 1) ? g.H0f1 : g.H0f0);     // H0[k-1]
        const short* h1f_in = (const short*)((k & 1) ? g.H1f0 : g.H1f1);     // H1[k-2]
        short* h1f_out = (short*)((k & 1) ? g.H1f1 : g.H1f0);
        const float* h1l_in = (k & 1) ? g.H1l0 : g.H1l1;
        float* h1l_out = (k & 1) ? g.H1l1 : g.H1l0;
        float hp[4];
#pragma unroll
        for (int r = 0; r < 4; ++r)
          hp[r] = h1l_in[(size_t)((MT << 4) + (quad << 2) + r) * HDIM + n];
        f4v ar = z4, az = z4, ain = z4, ahn = z4;
        const short* pAx = h0f_in + aoff;
        const short* pAh = h1f_in + aoff;
#pragma unroll 4
        for (int kc = 0; kc < 32; ++kc) {
          s8v Ax = ld8(pAx + kc * 512);
          s8v Ah = ld8(pAh + kc * 512);
          s8v Bir = ls[kc * 64 + ln];
          s8v Biz = ls[2048 + kc * 64 + ln];
          s8v Bin = ls[4096 + kc * 64 + ln];
          s8v Bhr = ld8(pH0 + kc * 512);
          s8v Bhz = ld8(pH1 + kc * 512);
          s8v Bhn = ld8(pH2 + kc * 512);
          ar = mfma_bf16(Ax, Bir, ar); ar = mfma_bf16(Ah, Bhr, ar);
          az = mfma_bf16(Ax, Biz, az); az = mfma_bf16(Ah, Bhz, az);
          ain = mfma_bf16(Ax, Bin, ain);
          ahn = mfma_bf16(Ah, Bhn, ahn);
        }
        short* fo = h1f_out + (((size_t)(MT * 32 + kc2)) << 9) + jp;
#pragma unroll
        for (int r = 0; r < 4; ++r) {
          const int m = (MT << 4) + (quad << 2) + r;
          float rr = sigf(ar[r] + br);
          float zz = sigf(az[r] + bz);
          float nn = tanhf(ain[r] + bin + rr * (ahn[r] + bhn));
          float hv = (1.f - zz) * nn + zz * hp[r];
          h1l_out[(size_t)m * HDIM + n] = hv;
          fo[((quad << 2) + r + (lhigh << 4)) * 8] = f2bs(hv);
        }
      }
      if (k < TLEN + 2) gridbar(g.bar, tid);
    }
  } else if (blk < 208) {
    // ================= OPG: logits, t = k-2 =================
    const int og = blk - 192;
    const int MT0 = w * 2;
    float bov[2];
    bov[0] = g.bo[og * 32 + l15];
    bov[1] = g.bo[og * 32 + 16 + l15];
    const int aoff = MT0 * 16384 + ln * 8;
    for (int k = 0; k <= TLEN + 2; ++k) {
      if (k >= 2 && k <= 257) {
        const short* h1f_in = (const short*)((k & 1) ? g.H1f0 : g.H1f1);     // H1[k-1]
        float* LG = (k & 1) ? g.LG1 : g.LG0;
        f4v acc[2][2] = {{z4, z4}, {z4, z4}};
        const short* pA = h1f_in + aoff;
#pragma unroll 4
        for (int kc = 0; kc < 32; ++kc) {
          s8v A0 = ld8(pA + kc * 512);
          s8v A1 = ld8(pA + 16384 + kc * 512);
          s8v B0 = ls[kc * 64 + ln];
          s8v B1 = ls[2048 + kc * 64 + ln];
          acc[0][0] = mfma_bf16(A0, B0, acc[0][0]);
          acc[0][1] = mfma_bf16(A0, B1, acc[0][1]);
          acc[1][0] = mfma_bf16(A1, B0, acc[1][0]);
          acc[1][1] = mfma_bf16(A1, B1, acc[1][1]);
        }
#pragma unroll
        for (int mi = 0; mi < 2; ++mi)
#pragma unroll
          for (int u = 0; u < 2; ++u)
#pragma unroll
            for (int r = 0; r < 4; ++r) {
              const int m = ((MT0 + mi) << 4) + (quad << 2) + r;
              LG[((size_t)m << 9) + og * 32 + (u << 4) + l15] = acc[mi][u][r] + bov[u];
            }
      }
      if (k < TLEN + 2) gridbar(g.bar, tid);
    }
  } else {
    // ================= OPS: log-softmax, t = k-3 =================
    const int ob = blk - 208;
    const int row = ob * 32 + (tid >> 4);
    const int l16 = tid & 15;
    for (int k = 0; k <= TLEN + 2; ++k) {
      if (k >= 3) {
        const int t = k - 3;
        const float* lr = ((k & 1) ? g.LG0 : g.LG1) + ((size_t)row << 9);
        float v[32];
        float mx = -1e30f;
#pragma unroll
        for (int j = 0; j < 32; ++j) { v[j] = lr[l16 + (j << 4)]; mx = fmaxf(mx, v[j]); }
#pragma unroll
        for (int o = 8; o > 0; o >>= 1) mx = fmaxf(mx, __shfl_xor(mx, o));
        float sum = 0.f;
#pragma unroll
        for (int j = 0; j < 32; ++j) sum += expf(v[j] - mx);
#pragma unroll
        for (int o = 8; o > 0; o >>= 1) sum += __shfl_xor(sum, o);
        const float lse = mx + logf(sum);
        float* orow = g.out + ((size_t)row * TLEN + t) * VDIM;
#pragma unroll
        for (int j = 0; j < 32; ++j) orow[l16 + (j << 4)] = v[j] - lse;
      }
      if (k < TLEN + 2) gridbar(g.bar, tid);
    }
  }
}

// ============ final: h_final [2,B,H] (natural layout -> plain concat copy) ============
__global__ __launch_bounds__(256) void unperm_hfinal(const float* __restrict__ h0l,
                                                     const float* __restrict__ h1l,
                                                     float* __restrict__ out) {
  int idx = blockIdx.x * 256 + threadIdx.x;   // 2*B*H
  const int BH = BATCH * HDIM;
  out[idx] = (idx < BH) ? h0l[idx] : h1l[idx - BH];
}

extern "C" void kernel_launch(void* const* d_in, const int* in_sizes, int n_in,
                              void* d_out, int out_size, void* d_ws, size_t ws_size,
                              hipStream_t stream) {
  const float* fps    = (const float*)d_in[1];
  const int* target   = (const int*)d_in[2];
  const float* emb    = (const float*)d_in[3];
  const float* Wc     = (const float*)d_in[4];
  const float* bc     = (const float*)d_in[5];
  const float* W_ih   = (const float*)d_in[6];   // [2,3H,H]
  const float* W_hh   = (const float*)d_in[7];
  const float* b_ih   = (const float*)d_in[8];
  const float* b_hh   = (const float*)d_in[9];
  const float* Wo     = (const float*)d_in[10];
  const float* bo     = (const float*)d_in[11];
  float* out = (float*)d_out;

  const int BH = BATCH * HDIM;
  const size_t WN = (size_t)H3 * HDIM;

  char* p = (char*)d_ws;
  float* hstd  = (float*)p; p += (size_t)BH * 4;
  float* table = (float*)p; p += (size_t)VDIM * H3 * 4;
  float* H0l[2]; H0l[0] = (float*)p; p += (size_t)BH * 4; H0l[1] = (float*)p; p += (size_t)BH * 4;
  float* H1l[2]; H1l[0] = (float*)p; p += (size_t)BH * 4; H1l[1] = (float*)p; p += (size_t)BH * 4;
  bf16* H0f[2]; H0f[0] = (bf16*)p; p += (size_t)BH * 2; H0f[1] = (bf16*)p; p += (size_t)BH * 2;
  bf16* H1f[2]; H1f[0] = (bf16*)p; p += (size_t)BH * 2; H1f[1] = (bf16*)p; p += (size_t)BH * 2;
  bf16* Whh0f = (bf16*)p; p += WN * 2;
  bf16* Wih1f = (bf16*)p; p += WN * 2;
  bf16* Whh1f = (bf16*)p; p += WN * 2;
  bf16* Wof   = (bf16*)p; p += (size_t)VDIM * HDIM * 2;
  float* LG0  = (float*)p; p += (size_t)BATCH * VDIM * 4;
  float* LG1  = (float*)p; p += (size_t)BATCH * VDIM * 4;
  unsigned* bar = (unsigned*)p; p += 64;

  static bool attr_done = false;
  if (!attr_done) {
    hipFuncSetAttribute(reinterpret_cast<const void*>(step_persist),
                        hipFuncAttributeMaxDynamicSharedMemorySize, 96 * 1024);
    attr_done = true;
  }

  hipMemsetAsync(bar, 0, 8, stream);

  // one-time weight shuffles into fragment blobs
  {
    int ng3 = (H3 / 16) * 32 * 64;             // 393216
    shuffle_w<<<ng3 / 256, 256, 0, stream>>>(W_hh, Whh0f, ng3);
    shuffle_w<<<ng3 / 256, 256, 0, stream>>>(W_ih + WN, Wih1f, ng3);
    shuffle_w<<<ng3 / 256, 256, 0, stream>>>(W_hh + WN, Whh1f, ng3);
    int ngv = (VDIM / 16) * 32 * 64;           // 65536
    shuffle_w<<<ngv / 256, 256, 0, stream>>>(Wo, Wof, ngv);
  }
  // init hidden: hstd = relu(fps @ Wc^T + bc)
  {
    GemmArgs a; a.A = fps; a.W = Wc; a.bias = bc; a.bias2 = nullptr;
    a.C = hstd; a.ldc = HDIM; a.K = FPDIM; a.reluA = 0; a.reluC = 1; a.b2lim = 0;
    gemm_bt<<<dim3(HDIM / 64, BATCH / 64), 256, 0, stream>>>(a);
  }
  // gi0 table = relu(emb) @ Wih0^T + b_ih0 + b_hh0 (r,z parts only)
  {
    GemmArgs a; a.A = emb; a.W = W_ih; a.bias = b_ih; a.bias2 = b_hh;
    a.C = table; a.ldc = H3; a.K = HDIM; a.reluA = 1; a.reluC = 0; a.b2lim = 2048;
    gemm_bt<<<dim3(H3 / 64, VDIM / 64), 256, 0, stream>>>(a);
  }
  // init hidden into fp32 state (natural layout) + frag blobs (parity-0 buffers)
  copy2<<<BH / 256, 256, 0, stream>>>(hstd, H0l[0], H1l[0]);
  permute_frag<<<(BATCH / 16) * 32 * 64 / 256, 256, 0, stream>>>(hstd, H0f[0], H1f[0]);

  // the persistent decoder
  PArgs pa;
  pa.target = target; pa.table = table; pa.bhh0n = b_hh + 2048;
  pa.bih1 = b_ih + H3; pa.bhh1 = b_hh + H3; pa.bo = bo;
  pa.Whh1 = Whh1f;
  pa.H0f0 = H0f[0]; pa.H0f1 = H0f[1]; pa.H1f0 = H1f[0]; pa.H1f1 = H1f[1];
  pa.H0l0 = H0l[0]; pa.H0l1 = H0l[1]; pa.H1l0 = H1l[0]; pa.H1l1 = H1l[1];
  pa.LG0 = LG0; pa.LG1 = LG1;
  pa.out = out; pa.bar = bar;
  pa.Whh0 = Whh0f; pa.Wih1 = Wih1f; pa.Wof = Wof;
  step_persist<<<NBLK, 512, 96 * 1024, stream>>>(pa);

  // h_final = [H0[256], H1[256]] (both land in parity-0 buffers)
  unperm_hfinal<<<2 * BH / 256, 256, 0, stream>>>(H0l[0], H1l[0],
                                                  out + (size_t)BATCH * TLEN * VDIM);
}

// Round 4
// 8298.147 us; speedup vs baseline: 3.4855x; 3.4855x over previous
//
#include <hip/hip_runtime.h>
#include <hip/hip_bf16.h>

#define HDIM 1024
#define VDIM 512
#define TLEN 256
#define BATCH 256
#define FPDIM 2048
#define H3 3072
#define NBLK 216
#define NXCD 8

typedef __hip_bfloat16 bf16;
typedef __attribute__((ext_vector_type(8))) short s8v;    // 8 bf16 (4 VGPRs)
typedef __attribute__((ext_vector_type(4))) float f4v;    // MFMA C/D

__device__ __forceinline__ f4v mfma_bf16(s8v a, s8v b, f4v c) {
  return __builtin_amdgcn_mfma_f32_16x16x32_bf16(a, b, c, 0, 0, 0);
}
__device__ __forceinline__ s8v ld8(const short* p) { return *(const s8v*)p; }
__device__ __forceinline__ float sigf(float x) { return 1.f / (1.f + expf(-x)); }
// fp32 -> bf16 bits, RNE
__device__ __forceinline__ short f2bs(float f) {
  union { float f; unsigned u; } c; c.f = f;
  unsigned u = c.u + 0x7fff + ((c.u >> 16) & 1);
  return (short)(u >> 16);
}

__device__ __forceinline__ unsigned aload(const unsigned* p) {
  return __hip_atomic_load(p, __ATOMIC_RELAXED, __HIP_MEMORY_SCOPE_AGENT);
}
__device__ __forceinline__ void astore(unsigned* p, unsigned v) {
  __hip_atomic_store(p, v, __ATOMIC_RELAXED, __HIP_MEMORY_SCOPE_AGENT);
}

// ============ one-time: fp32 [N,1024] -> bf16 MFMA-frag blob ============
// blob[((nt*32+kc)*64 + lane)*8 + j]; n = nt*16+(lane&15), k = kc*32+(lane>>4)*8+j
__global__ __launch_bounds__(256) void shuffle_w(const float* __restrict__ src,
                                                 bf16* __restrict__ dst, int ngroups) {
  int g = blockIdx.x * 256 + threadIdx.x;
  if (g >= ngroups) return;
  int lane = g & 63, kc = (g >> 6) & 31, nt = g >> 11;
  int n = nt * 16 + (lane & 15);
  int k = kc * 32 + ((lane >> 4) << 3);
  const float* s = src + (size_t)n * HDIM + k;
  short* d = (short*)dst + (size_t)g * 8;
  s8v v;
#pragma unroll
  for (int j = 0; j < 8; ++j) v[j] = f2bs(s[j]);
  *(s8v*)d = v;
}

// ============ one-time fp32 tile GEMM: C = [relu](A[M,K] @ W[N,K]^T + bias [+bias2 if n<lim]) ============
struct GemmArgs {
  const float* A; const float* W; const float* bias; const float* bias2;
  float* C; int ldc; int K; int reluA; int reluC; int b2lim;
};
#define LDP 68
__global__ __launch_bounds__(256) void gemm_bt(GemmArgs g) {
  __shared__ float As[16][LDP];
  __shared__ float Ws[16][LDP];
  const int tid = threadIdx.x;
  const int tx = tid & 15, ty = tid >> 4;
  const int m0 = blockIdx.y * 64, n0 = blockIdx.x * 64;
  float acc[4][4] = {{0.f, 0.f, 0.f, 0.f}};
  const int K = g.K;
  for (int kb = 0; kb < K / 16; ++kb) {
    const int k0 = kb * 16;
#pragma unroll
    for (int i = 0; i < 4; ++i) {
      int idx = tid + i * 256;
      int ml = idx >> 4, kl = idx & 15;
      float a = g.A[(size_t)(m0 + ml) * K + k0 + kl];
      if (g.reluA) a = fmaxf(a, 0.f);
      As[kl][ml] = a;
      Ws[kl][ml] = g.W[(size_t)(n0 + ml) * K + k0 + kl];
    }
    __syncthreads();
#pragma unroll
    for (int k = 0; k < 16; ++k) {
      float4 av = *(const float4*)&As[k][ty * 4];
      float4 wv = *(const float4*)&Ws[k][tx * 4];
      float a[4] = {av.x, av.y, av.z, av.w};
      float w[4] = {wv.x, wv.y, wv.z, wv.w};
#pragma unroll
      for (int i = 0; i < 4; ++i)
#pragma unroll
        for (int j = 0; j < 4; ++j)
          acc[i][j] = fmaf(a[i], w[j], acc[i][j]);
    }
    __syncthreads();
  }
#pragma unroll
  for (int i = 0; i < 4; ++i) {
    int m = m0 + ty * 4 + i;
#pragma unroll
    for (int j = 0; j < 4; ++j) {
      int n = n0 + tx * 4 + j;
      float v = acc[i][j] + g.bias[n];
      if (g.bias2 && n < g.b2lim) v += g.bias2[n];
      if (g.reluC) v = fmaxf(v, 0.f);
      g.C[(size_t)m * g.ldc + n] = v;
    }
  }
}

// ============ one-time: duplicate init hidden into both layers' fp32 state bufs ============
__global__ __launch_bounds__(256) void copy2(const float* __restrict__ s,
                                             float* __restrict__ d0,
                                             float* __restrict__ d1) {
  int i = blockIdx.x * 256 + threadIdx.x;
  float v = s[i];
  d0[i] = v; d1[i] = v;
}

// init hidden -> frag blobs (both layers)
__global__ __launch_bounds__(256) void permute_frag(const float* __restrict__ s,
                                                    bf16* __restrict__ d0,
                                                    bf16* __restrict__ d1) {
  int g = blockIdx.x * 256 + threadIdx.x;      // (B/16)*32*64 groups
  int lane = g & 63, kc = (g >> 6) & 31, mt = g >> 11;
  int m = mt * 16 + (lane & 15), k = kc * 32 + ((lane >> 4) << 3);
  const float* src = s + (size_t)m * HDIM + k;
  s8v v;
#pragma unroll
  for (int j = 0; j < 8; ++j) v[j] = f2bs(src[j]);
  *(s8v*)((short*)d0 + (size_t)g * 8) = v;
  *(s8v*)((short*)d1 + (size_t)g * 8) = v;
}

// ============ persistent fused decoder ============
// ONE kernel for all 256 steps. 216 blocks x 512 thr, 1 block/CU (96 KB LDS).
// Roles: blk 0..63 L0 | 64..191 L1 | 192..207 OPG | 208..215 OPS.
// Barrier v2: per-block arrival flags (own cacheline, monotonic gen);
// ONE release fence (buffer_wbl2) per XCD by an elected leader;
// per-block acquire fence (buffer_inv only, cheap, dirty-preserving).
struct PArgs {
  const int* target;
  const float* table;          // [V,3H] fp32
  const float* bhh0n;          // b_hh0 + 2048
  const float* bih1; const float* bhh1; const float* bo;
  const bf16* Whh1;            // L1 h-src weight blob (streamed per step)
  bf16 *H0f0, *H0f1, *H1f0, *H1f1;
  float *H0l0, *H0l1, *H1l0, *H1l1;
  float *LG0, *LG1;            // logits double buffer [256][512] f32
  float* out;
  unsigned* arrive;            // [NBLK] padded x16 (64B lines)
  unsigned* done;              // [NXCD] padded x16
  unsigned* lead;              // [NXCD] padded x16, leader block id or ~0u
  const bf16 *Whh0, *Wih1, *Wof;   // blobs for LDS staging
};

__device__ __forceinline__ void gridbar(unsigned* arrive, unsigned* done,
                                        unsigned gen, int mylead, unsigned amask,
                                        int tid, int blk) {
  __syncthreads();   // all waves' stores drained (vmcnt0) into local L2
  if (tid == 0) astore(arrive + blk * 16, gen);
  if (mylead >= 0) {                     // this block is leader of XCD 'mylead'
    if (tid < NBLK) {
      while (aload(arrive + tid * 16) < gen) __builtin_amdgcn_s_sleep(1);
    }
    __syncthreads();                     // all arrivals confirmed
    if (tid == 0) {
      __builtin_amdgcn_fence(__ATOMIC_RELEASE, "agent");   // wbl2: flush this XCD's L2
      astore(done + mylead * 16, gen);
    }
  }
  if (tid < NXCD && ((amask >> tid) & 1u)) {
    while (aload(done + tid * 16) < gen) __builtin_amdgcn_s_sleep(1);
  }
  __syncthreads();
  if (tid == 0) __builtin_amdgcn_fence(__ATOMIC_ACQUIRE, "agent");  // buffer_inv
  __syncthreads();
}

__global__ __launch_bounds__(512, 2) void step_persist(PArgs g) {
  extern __shared__ short lds[];               // 96 KB dynamic
  __shared__ int sb_lead;
  __shared__ unsigned sb_amask;
  const int blk = blockIdx.x, tid = threadIdx.x;
  const int w = tid >> 6, ln = tid & 63, l15 = ln & 15, quad = ln >> 4;
  s8v* ls = (s8v*)lds;

  // ---- leader election (once) ----
  unsigned xcd;
  asm volatile("s_getreg_b32 %0, hwreg(HW_REG_XCC_ID)" : "=s"(xcd));
  xcd &= 7;
  if (tid == 0) {
    unsigned exp = 0xFFFFFFFFu;
    __hip_atomic_compare_exchange_strong(g.lead + xcd * 16, &exp, (unsigned)blk,
        __ATOMIC_ACQ_REL, __ATOMIC_RELAXED, __HIP_MEMORY_SCOPE_AGENT);
    astore(g.arrive + blk * 16, 1u);
  }

  // ---- stage this block's static weight slice into LDS (overlaps election) ----
  if (blk < 64) {
    const int hg = blk;
#pragma unroll
    for (int gi = 0; gi < 3; ++gi) {
      const s8v* src = (const s8v*)((const short*)g.Whh0 + (size_t)(gi * 64 + hg) * 16384);
      for (int i = tid; i < 2048; i += 512) ls[gi * 2048 + i] = src[i];
    }
  } else if (blk < 192) {
    const int ng = (blk - 64) & 63;
#pragma unroll
    for (int gi = 0; gi < 3; ++gi) {
      const s8v* src = (const s8v*)((const short*)g.Wih1 + (size_t)(gi * 64 + ng) * 16384);
      for (int i = tid; i < 2048; i += 512) ls[gi * 2048 + i] = src[i];
    }
  } else if (blk < 208) {
    const int og = blk - 192;
#pragma unroll
    for (int u = 0; u < 2; ++u) {
      const s8v* src = (const s8v*)((const short*)g.Wof + (size_t)(og * 2 + u) * 16384);
      for (int i = tid; i < 2048; i += 512) ls[u * 2048 + i] = src[i];
    }
  }

  // ---- init handshake: all blocks resident & elections done (no fences needed:
  //      CAS and flag ops are coherent atomics) ----
  if (tid < NBLK) {
    while (aload(g.arrive + tid * 16) < 1u) __builtin_amdgcn_s_sleep(1);
  }
  __syncthreads();
  if (tid == 0) {
    unsigned am = 0;
    for (int x = 0; x < NXCD; ++x)
      if (aload(g.lead + x * 16) != 0xFFFFFFFFu) am |= (1u << x);
    sb_amask = am;
    sb_lead = (aload(g.lead + xcd * 16) == (unsigned)blk) ? (int)xcd : -1;
  }
  __syncthreads();
  const int mylead = sb_lead;
  const unsigned amask = sb_amask;

  const f4v z4 = {0.f, 0.f, 0.f, 0.f};

  if (blk < 64) {
    // ================= L0: t = k =================
    const int hg = blk;
    const int MT0 = w * 2;
    const int n = hg * 16 + l15;
    const float bhn = g.bhh0n[n];
    const int kc2 = hg >> 1;
    const int lhigh = ((hg & 1) << 1) + (l15 >> 3);
    const int jp = l15 & 7;
    const int aoff = MT0 * 16384 + ln * 8;
    for (int k = 0; k <= TLEN + 2; ++k) {
      if (k <= 255) {
        const short* h0f_in = (const short*)((k & 1) ? g.H0f1 : g.H0f0);
        short* h0f_out = (short*)((k & 1) ? g.H0f0 : g.H0f1);
        const float* h0l_in = (k & 1) ? g.H0l1 : g.H0l0;
        float* h0l_out = (k & 1) ? g.H0l0 : g.H0l1;
        float tr_[2][4], tz_[2][4], tn_[2][4], hp[2][4];
#pragma unroll
        for (int mi = 0; mi < 2; ++mi)
#pragma unroll
          for (int r = 0; r < 4; ++r) {
            const int m = ((MT0 + mi) << 4) + (quad << 2) + r;
            const int tok = k ? g.target[m * TLEN + k - 1] : 0;
            const float* trow = g.table + (size_t)tok * H3;
            tr_[mi][r] = trow[n];
            tz_[mi][r] = trow[n + 1024];
            tn_[mi][r] = trow[n + 2048];
            hp[mi][r] = h0l_in[(size_t)m * HDIM + n];
          }
        f4v a0[2] = {z4, z4}, a1[2] = {z4, z4}, a2[2] = {z4, z4};
        const short* pA = h0f_in + aoff;
#pragma unroll 4
        for (int kc = 0; kc < 32; ++kc) {
          s8v A0 = ld8(pA + kc * 512);
          s8v A1 = ld8(pA + 16384 + kc * 512);
          s8v B0 = ls[kc * 64 + ln];
          s8v B1 = ls[2048 + kc * 64 + ln];
          s8v B2 = ls[4096 + kc * 64 + ln];
          a0[0] = mfma_bf16(A0, B0, a0[0]); a0[1] = mfma_bf16(A1, B0, a0[1]);
          a1[0] = mfma_bf16(A0, B1, a1[0]); a1[1] = mfma_bf16(A1, B1, a1[1]);
          a2[0] = mfma_bf16(A0, B2, a2[0]); a2[1] = mfma_bf16(A1, B2, a2[1]);
        }
#pragma unroll
        for (int mi = 0; mi < 2; ++mi) {
          const int MT = MT0 + mi;
          short* fo = h0f_out + (((size_t)(MT * 32 + kc2)) << 9) + jp;
#pragma unroll
          for (int r = 0; r < 4; ++r) {
            const int m = (MT << 4) + (quad << 2) + r;
            float rr = sigf(tr_[mi][r] + a0[mi][r]);
            float zz = sigf(tz_[mi][r] + a1[mi][r]);
            float nn = tanhf(tn_[mi][r] + rr * (a2[mi][r] + bhn));
            float hv = (1.f - zz) * nn + zz * hp[mi][r];
            h0l_out[(size_t)m * HDIM + n] = hv;
            fo[((quad << 2) + r + (lhigh << 4)) * 8] = f2bs(hv);
          }
        }
      }
      if (k < TLEN + 2) gridbar(g.arrive, g.done, (unsigned)k + 2u, mylead, amask, tid, blk);
    }
  } else if (blk < 192) {
    // ================= L1: t = k-1 =================
    const int b1 = blk - 64;
    const int ng = b1 & 63, mg = b1 >> 6;
    const int MT = mg * 8 + w;
    const int n = ng * 16 + l15;
    const float br = g.bih1[n] + g.bhh1[n];
    const float bz = g.bih1[n + 1024] + g.bhh1[n + 1024];
    const float bin = g.bih1[n + 2048], bhn = g.bhh1[n + 2048];
    const int kc2 = ng >> 1;
    const int lhigh = ((ng & 1) << 1) + (l15 >> 3);
    const int jp = l15 & 7;
    const int aoff = MT * 16384 + ln * 8;
    const short* pH0 = (const short*)g.Whh1 + (size_t)(ng) * 16384 + ln * 8;
    const short* pH1 = (const short*)g.Whh1 + (size_t)(64 + ng) * 16384 + ln * 8;
    const short* pH2 = (const short*)g.Whh1 + (size_t)(128 + ng) * 16384 + ln * 8;
    for (int k = 0; k <= TLEN + 2; ++k) {
      if (k >= 1 && k <= 256) {
        const short* h0f_in = (const short*)((k & 1) ? g.H0f1 : g.H0f0);     // H0[k-1]
        const short* h1f_in = (const short*)((k & 1) ? g.H1f0 : g.H1f1);     // H1[k-2]
        short* h1f_out = (short*)((k & 1) ? g.H1f1 : g.H1f0);
        const float* h1l_in = (k & 1) ? g.H1l0 : g.H1l1;
        float* h1l_out = (k & 1) ? g.H1l1 : g.H1l0;
        float hp[4];
#pragma unroll
        for (int r = 0; r < 4; ++r)
          hp[r] = h1l_in[(size_t)((MT << 4) + (quad << 2) + r) * HDIM + n];
        f4v ar = z4, az = z4, ain = z4, ahn = z4;
        const short* pAx = h0f_in + aoff;
        const short* pAh = h1f_in + aoff;
#pragma unroll 4
        for (int kc = 0; kc < 32; ++kc) {
          s8v Ax = ld8(pAx + kc * 512);
          s8v Ah = ld8(pAh + kc * 512);
          s8v Bir = ls[kc * 64 + ln];
          s8v Biz = ls[2048 + kc * 64 + ln];
          s8v Bin = ls[4096 + kc * 64 + ln];
          s8v Bhr = ld8(pH0 + kc * 512);
          s8v Bhz = ld8(pH1 + kc * 512);
          s8v Bhn = ld8(pH2 + kc * 512);
          ar = mfma_bf16(Ax, Bir, ar); ar = mfma_bf16(Ah, Bhr, ar);
          az = mfma_bf16(Ax, Biz, az); az = mfma_bf16(Ah, Bhz, az);
          ain = mfma_bf16(Ax, Bin, ain);
          ahn = mfma_bf16(Ah, Bhn, ahn);
        }
        short* fo = h1f_out + (((size_t)(MT * 32 + kc2)) << 9) + jp;
#pragma unroll
        for (int r = 0; r < 4; ++r) {
          const int m = (MT << 4) + (quad << 2) + r;
          float rr = sigf(ar[r] + br);
          float zz = sigf(az[r] + bz);
          float nn = tanhf(ain[r] + bin + rr * (ahn[r] + bhn));
          float hv = (1.f - zz) * nn + zz * hp[r];
          h1l_out[(size_t)m * HDIM + n] = hv;
          fo[((quad << 2) + r + (lhigh << 4)) * 8] = f2bs(hv);
        }
      }
      if (k < TLEN + 2) gridbar(g.arrive, g.done, (unsigned)k + 2u, mylead, amask, tid, blk);
    }
  } else if (blk < 208) {
    // ================= OPG: logits, t = k-2 =================
    const int og = blk - 192;
    const int MT0 = w * 2;
    float bov[2];
    bov[0] = g.bo[og * 32 + l15];
    bov[1] = g.bo[og * 32 + 16 + l15];
    const int aoff = MT0 * 16384 + ln * 8;
    for (int k = 0; k <= TLEN + 2; ++k) {
      if (k >= 2 && k <= 257) {
        const short* h1f_in = (const short*)((k & 1) ? g.H1f0 : g.H1f1);     // H1[k-1]
        float* LG = (k & 1) ? g.LG1 : g.LG0;
        f4v acc[2][2] = {{z4, z4}, {z4, z4}};
        const short* pA = h1f_in + aoff;
#pragma unroll 4
        for (int kc = 0; kc < 32; ++kc) {
          s8v A0 = ld8(pA + kc * 512);
          s8v A1 = ld8(pA + 16384 + kc * 512);
          s8v B0 = ls[kc * 64 + ln];
          s8v B1 = ls[2048 + kc * 64 + ln];
          acc[0][0] = mfma_bf16(A0, B0, acc[0][0]);
          acc[0][1] = mfma_bf16(A0, B1, acc[0][1]);
          acc[1][0] = mfma_bf16(A1, B0, acc[1][0]);
          acc[1][1] = mfma_bf16(A1, B1, acc[1][1]);
        }
#pragma unroll
        for (int mi = 0; mi < 2; ++mi)
#pragma unroll
          for (int u = 0; u < 2; ++u)
#pragma unroll
            for (int r = 0; r < 4; ++r) {
              const int m = ((MT0 + mi) << 4) + (quad << 2) + r;
              LG[((size_t)m << 9) + og * 32 + (u << 4) + l15] = acc[mi][u][r] + bov[u];
            }
      }
      if (k < TLEN + 2) gridbar(g.arrive, g.done, (unsigned)k + 2u, mylead, amask, tid, blk);
    }
  } else {
    // ================= OPS: log-softmax, t = k-3 =================
    const int ob = blk - 208;
    const int row = ob * 32 + (tid >> 4);
    const int l16 = tid & 15;
    for (int k = 0; k <= TLEN + 2; ++k) {
      if (k >= 3) {
        const int t = k - 3;
        const float* lr = ((k & 1) ? g.LG0 : g.LG1) + ((size_t)row << 9);
        float v[32];
        float mx = -1e30f;
#pragma unroll
        for (int j = 0; j < 32; ++j) { v[j] = lr[l16 + (j << 4)]; mx = fmaxf(mx, v[j]); }
#pragma unroll
        for (int o = 8; o > 0; o >>= 1) mx = fmaxf(mx, __shfl_xor(mx, o));
        float sum = 0.f;
#pragma unroll
        for (int j = 0; j < 32; ++j) sum += expf(v[j] - mx);
#pragma unroll
        for (int o = 8; o > 0; o >>= 1) sum += __shfl_xor(sum, o);
        const float lse = mx + logf(sum);
        float* orow = g.out + ((size_t)row * TLEN + t) * VDIM;
#pragma unroll
        for (int j = 0; j < 32; ++j) orow[l16 + (j << 4)] = v[j] - lse;
      }
      if (k < TLEN + 2) gridbar(g.arrive, g.done, (unsigned)k + 2u, mylead, amask, tid, blk);
    }
  }
}

// ============ final: h_final [2,B,H] (natural layout -> plain concat copy) ============
__global__ __launch_bounds__(256) void unperm_hfinal(const float* __restrict__ h0l,
                                                     const float* __restrict__ h1l,
                                                     float* __restrict__ out) {
  int idx = blockIdx.x * 256 + threadIdx.x;   // 2*B*H
  const int BH = BATCH * HDIM;
  out[idx] = (idx < BH) ? h0l[idx] : h1l[idx - BH];
}

extern "C" void kernel_launch(void* const* d_in, const int* in_sizes, int n_in,
                              void* d_out, int out_size, void* d_ws, size_t ws_size,
                              hipStream_t stream) {
  const float* fps    = (const float*)d_in[1];
  const int* target   = (const int*)d_in[2];
  const float* emb    = (const float*)d_in[3];
  const float* Wc     = (const float*)d_in[4];
  const float* bc     = (const float*)d_in[5];
  const float* W_ih   = (const float*)d_in[6];   // [2,3H,H]
  const float* W_hh   = (const float*)d_in[7];
  const float* b_ih   = (const float*)d_in[8];
  const float* b_hh   = (const float*)d_in[9];
  const float* Wo     = (const float*)d_in[10];
  const float* bo     = (const float*)d_in[11];
  float* out = (float*)d_out;

  const int BH = BATCH * HDIM;
  const size_t WN = (size_t)H3 * HDIM;

  char* p = (char*)d_ws;
  float* hstd  = (float*)p; p += (size_t)BH * 4;
  float* table = (float*)p; p += (size_t)VDIM * H3 * 4;
  float* H0l[2]; H0l[0] = (float*)p; p += (size_t)BH * 4; H0l[1] = (float*)p; p += (size_t)BH * 4;
  float* H1l[2]; H1l[0] = (float*)p; p += (size_t)BH * 4; H1l[1] = (float*)p; p += (size_t)BH * 4;
  bf16* H0f[2]; H0f[0] = (bf16*)p; p += (size_t)BH * 2; H0f[1] = (bf16*)p; p += (size_t)BH * 2;
  bf16* H1f[2]; H1f[0] = (bf16*)p; p += (size_t)BH * 2; H1f[1] = (bf16*)p; p += (size_t)BH * 2;
  bf16* Whh0f = (bf16*)p; p += WN * 2;
  bf16* Wih1f = (bf16*)p; p += WN * 2;
  bf16* Whh1f = (bf16*)p; p += WN * 2;
  bf16* Wof   = (bf16*)p; p += (size_t)VDIM * HDIM * 2;
  float* LG0  = (float*)p; p += (size_t)BATCH * VDIM * 4;
  float* LG1  = (float*)p; p += (size_t)BATCH * VDIM * 4;
  unsigned* arrive = (unsigned*)p; p += (size_t)NBLK * 64;
  unsigned* done   = (unsigned*)p; p += (size_t)NXCD * 64;
  unsigned* lead   = (unsigned*)p; p += (size_t)NXCD * 64;

  static bool attr_done = false;
  if (!attr_done) {
    hipFuncSetAttribute(reinterpret_cast<const void*>(step_persist),
                        hipFuncAttributeMaxDynamicSharedMemorySize, 96 * 1024);
    attr_done = true;
  }

  hipMemsetAsync(arrive, 0, (size_t)NBLK * 64, stream);
  hipMemsetAsync(done, 0, (size_t)NXCD * 64, stream);
  hipMemsetAsync(lead, 0xFF, (size_t)NXCD * 64, stream);

  // one-time weight shuffles into fragment blobs
  {
    int ng3 = (H3 / 16) * 32 * 64;             // 393216
    shuffle_w<<<ng3 / 256, 256, 0, stream>>>(W_hh, Whh0f, ng3);
    shuffle_w<<<ng3 / 256, 256, 0, stream>>>(W_ih + WN, Wih1f, ng3);
    shuffle_w<<<ng3 / 256, 256, 0, stream>>>(W_hh + WN, Whh1f, ng3);
    int ngv = (VDIM / 16) * 32 * 64;           // 65536
    shuffle_w<<<ngv / 256, 256, 0, stream>>>(Wo, Wof, ngv);
  }
  // init hidden: hstd = relu(fps @ Wc^T + bc)
  {
    GemmArgs a; a.A = fps; a.W = Wc; a.bias = bc; a.bias2 = nullptr;
    a.C = hstd; a.ldc = HDIM; a.K = FPDIM; a.reluA = 0; a.reluC = 1; a.b2lim = 0;
    gemm_bt<<<dim3(HDIM / 64, BATCH / 64), 256, 0, stream>>>(a);
  }
  // gi0 table = relu(emb) @ Wih0^T + b_ih0 + b_hh0 (r,z parts only)
  {
    GemmArgs a; a.A = emb; a.W = W_ih; a.bias = b_ih; a.bias2 = b_hh;
    a.C = table; a.ldc = H3; a.K = HDIM; a.reluA = 1; a.reluC = 0; a.b2lim = 2048;
    gemm_bt<<<dim3(H3 / 64, VDIM / 64), 256, 0, stream>>>(a);
  }
  // init hidden into fp32 state (natural layout) + frag blobs (parity-0 buffers)
  copy2<<<BH / 256, 256, 0, stream>>>(hstd, H0l[0], H1l[0]);
  permute_frag<<<(BATCH / 16) * 32 * 64 / 256, 256, 0, stream>>>(hstd, H0f[0], H1f[0]);

  // the persistent decoder
  PArgs pa;
  pa.target = target; pa.table = table; pa.bhh0n = b_hh + 2048;
  pa.bih1 = b_ih + H3; pa.bhh1 = b_hh + H3; pa.bo = bo;
  pa.Whh1 = Whh1f;
  pa.H0f0 = H0f[0]; pa.H0f1 = H0f[1]; pa.H1f0 = H1f[0]; pa.H1f1 = H1f[1];
  pa.H0l0 = H0l[0]; pa.H0l1 = H0l[1]; pa.H1l0 = H1l[0]; pa.H1l1 = H1l[1];
  pa.LG0 = LG0; pa.LG1 = LG1;
  pa.out = out;
  pa.arrive = arrive; pa.done = done; pa.lead = lead;
  pa.Whh0 = Whh0f; pa.Wih1 = Wih1f; pa.Wof = Wof;
  step_persist<<<NBLK, 512, 96 * 1024, stream>>>(pa);

  // h_final = [H0[256], H1[256]] (both land in parity-0 buffers)
  unperm_hfinal<<<2 * BH / 256, 256, 0, stream>>>(H0l[0], H1l[0],
                                                  out + (size_t)BATCH * TLEN * VDIM);
}

// Round 5
// 7864.828 us; speedup vs baseline: 3.6775x; 1.0551x over previous
//
#include <hip/hip_runtime.h>
#include <hip/hip_bf16.h>

#define HDIM 1024
#define VDIM 512
#define TLEN 256
#define BATCH 256
#define FPDIM 2048
#define H3 3072
#define NBLK 216
#define NXCD 8

typedef __hip_bfloat16 bf16;
typedef __attribute__((ext_vector_type(8))) short s8v;    // 8 bf16 (4 VGPRs)
typedef __attribute__((ext_vector_type(4))) float f4v;    // MFMA C/D

__device__ __forceinline__ f4v mfma_bf16(s8v a, s8v b, f4v c) {
  return __builtin_amdgcn_mfma_f32_16x16x32_bf16(a, b, c, 0, 0, 0);
}
__device__ __forceinline__ s8v ld8(const short* p) { return *(const s8v*)p; }
__device__ __forceinline__ float sigf(float x) { return 1.f / (1.f + expf(-x)); }
// fp32 -> bf16 bits, RNE
__device__ __forceinline__ short f2bs(float f) {
  union { float f; unsigned u; } c; c.f = f;
  unsigned u = c.u + 0x7fff + ((c.u >> 16) & 1);
  return (short)(u >> 16);
}

__device__ __forceinline__ unsigned aload(const unsigned* p) {
  return __hip_atomic_load(p, __ATOMIC_RELAXED, __HIP_MEMORY_SCOPE_AGENT);
}
__device__ __forceinline__ void astore(unsigned* p, unsigned v) {
  __hip_atomic_store(p, v, __ATOMIC_RELAXED, __HIP_MEMORY_SCOPE_AGENT);
}

// ============ one-time: fp32 [N,1024] -> bf16 MFMA-frag blob ============
// blob[((nt*32+kc)*64 + lane)*8 + j]; n = nt*16+(lane&15), k = kc*32+(lane>>4)*8+j
__global__ __launch_bounds__(256) void shuffle_w(const float* __restrict__ src,
                                                 bf16* __restrict__ dst, int ngroups) {
  int g = blockIdx.x * 256 + threadIdx.x;
  if (g >= ngroups) return;
  int lane = g & 63, kc = (g >> 6) & 31, nt = g >> 11;
  int n = nt * 16 + (lane & 15);
  int k = kc * 32 + ((lane >> 4) << 3);
  const float* s = src + (size_t)n * HDIM + k;
  short* d = (short*)dst + (size_t)g * 8;
  s8v v;
#pragma unroll
  for (int j = 0; j < 8; ++j) v[j] = f2bs(s[j]);
  *(s8v*)d = v;
}

// ============ one-time fp32 tile GEMM: C = [relu](A[M,K] @ W[N,K]^T + bias [+bias2 if n<lim]) ============
struct GemmArgs {
  const float* A; const float* W; const float* bias; const float* bias2;
  float* C; int ldc; int K; int reluA; int reluC; int b2lim;
};
#define LDP 68
__global__ __launch_bounds__(256) void gemm_bt(GemmArgs g) {
  __shared__ float As[16][LDP];
  __shared__ float Ws[16][LDP];
  const int tid = threadIdx.x;
  const int tx = tid & 15, ty = tid >> 4;
  const int m0 = blockIdx.y * 64, n0 = blockIdx.x * 64;
  float acc[4][4] = {{0.f, 0.f, 0.f, 0.f}};
  const int K = g.K;
  for (int kb = 0; kb < K / 16; ++kb) {
    const int k0 = kb * 16;
#pragma unroll
    for (int i = 0; i < 4; ++i) {
      int idx = tid + i * 256;
      int ml = idx >> 4, kl = idx & 15;
      float a = g.A[(size_t)(m0 + ml) * K + k0 + kl];
      if (g.reluA) a = fmaxf(a, 0.f);
      As[kl][ml] = a;
      Ws[kl][ml] = g.W[(size_t)(n0 + ml) * K + k0 + kl];
    }
    __syncthreads();
#pragma unroll
    for (int k = 0; k < 16; ++k) {
      float4 av = *(const float4*)&As[k][ty * 4];
      float4 wv = *(const float4*)&Ws[k][tx * 4];
      float a[4] = {av.x, av.y, av.z, av.w};
      float w[4] = {wv.x, wv.y, wv.z, wv.w};
#pragma unroll
      for (int i = 0; i < 4; ++i)
#pragma unroll
        for (int j = 0; j < 4; ++j)
          acc[i][j] = fmaf(a[i], w[j], acc[i][j]);
    }
    __syncthreads();
  }
#pragma unroll
  for (int i = 0; i < 4; ++i) {
    int m = m0 + ty * 4 + i;
#pragma unroll
    for (int j = 0; j < 4; ++j) {
      int n = n0 + tx * 4 + j;
      float v = acc[i][j] + g.bias[n];
      if (g.bias2 && n < g.b2lim) v += g.bias2[n];
      if (g.reluC) v = fmaxf(v, 0.f);
      g.C[(size_t)m * g.ldc + n] = v;
    }
  }
}

// ============ one-time: duplicate init hidden into both layers' fp32 state bufs ============
__global__ __launch_bounds__(256) void copy2(const float* __restrict__ s,
                                             float* __restrict__ d0,
                                             float* __restrict__ d1) {
  int i = blockIdx.x * 256 + threadIdx.x;
  float v = s[i];
  d0[i] = v; d1[i] = v;
}

// init hidden -> frag blobs (both layers)
__global__ __launch_bounds__(256) void permute_frag(const float* __restrict__ s,
                                                    bf16* __restrict__ d0,
                                                    bf16* __restrict__ d1) {
  int g = blockIdx.x * 256 + threadIdx.x;      // (B/16)*32*64 groups
  int lane = g & 63, kc = (g >> 6) & 31, mt = g >> 11;
  int m = mt * 16 + (lane & 15), k = kc * 32 + ((lane >> 4) << 3);
  const float* src = s + (size_t)m * HDIM + k;
  s8v v;
#pragma unroll
  for (int j = 0; j < 8; ++j) v[j] = f2bs(src[j]);
  *(s8v*)((short*)d0 + (size_t)g * 8) = v;
  *(s8v*)((short*)d1 + (size_t)g * 8) = v;
}

// ============ persistent fused decoder ============
// ONE kernel for all 256 steps. 216 blocks x 512 thr, 1 block/CU (96 KB LDS).
// Roles: blk 0..63 L0 | 64..191 L1 | 192..207 OPG | 208..215 OPS.
// Barrier v3: per-block arrival flags; each XCD leader waits only for its OWN
// XCD's arrivals, does ONE wbl2 (release), sets done[xcd]; after all dones the
// leader does ONE buffer_inv (acquire) and sets go[xcd]; non-leader blocks spin
// on their local go line only.  8 wbl2 + 8 inv per step (was 8 + 216).
struct PArgs {
  const int* target;
  const float* table;          // [V,3H] fp32
  const float* bhh0n;          // b_hh0 + 2048
  const float* bih1; const float* bhh1; const float* bo;
  const bf16* Whh1;            // L1 h-src weight blob (streamed per step)
  bf16 *H0f0, *H0f1, *H1f0, *H1f1;
  float *H0l0, *H0l1, *H1l0, *H1l1;
  float *LG0, *LG1;            // logits double buffer [256][512] f32
  float* out;
  unsigned* arrive;            // [NBLK] padded x16 (64B lines)
  unsigned* done;              // [NXCD] padded x16
  unsigned* lead;              // [NXCD] padded x16, leader block id or ~0u
  unsigned* go;                // [NXCD] padded x16
  unsigned* bxcd;              // [NBLK] padded x16, block -> xcd map
  const bf16 *Whh0, *Wih1, *Wof;   // blobs for LDS staging
};

__device__ __forceinline__ void gridbar(unsigned* arrive, unsigned* done,
                                        unsigned* goflag, unsigned gen,
                                        int mylead, unsigned amask, bool mine,
                                        int tid, int blk) {
  __syncthreads();   // all waves' stores drained (vmcnt0) into this XCD's L2
  if (tid == 0) astore(arrive + blk * 16, gen);
  if (mylead >= 0) {                     // this block is leader of XCD 'mylead'
    if (mine) {                          // mine => tid<NBLK and bxcd[tid]==my xcd
      while (aload(arrive + tid * 16) < gen) __builtin_amdgcn_s_sleep(1);
    }
    __syncthreads();                     // own-XCD arrivals confirmed
    if (tid == 0) {
      __builtin_amdgcn_fence(__ATOMIC_RELEASE, "agent");   // wbl2: flush own L2 -> L3
      astore(done + mylead * 16, gen);
    }
    if (tid < NXCD && ((amask >> tid) & 1u)) {
      while (aload(done + tid * 16) < gen) __builtin_amdgcn_s_sleep(1);
    }
    __syncthreads();                     // all XCDs flushed
    if (tid == 0) {
      __builtin_amdgcn_fence(__ATOMIC_ACQUIRE, "agent");   // ONE inv for this XCD
      astore(goflag, gen);
    }
    __syncthreads();
  } else {
    if (tid == 0) {
      while (aload(goflag) < gen) __builtin_amdgcn_s_sleep(1);
    }
    __syncthreads();
  }
}

__global__ __launch_bounds__(512, 2) void step_persist(PArgs g) {
  extern __shared__ short lds[];               // 96 KB dynamic
  __shared__ int sb_lead;
  __shared__ unsigned sb_amask;
  const int blk = blockIdx.x, tid = threadIdx.x;
  const int w = tid >> 6, ln = tid & 63, l15 = ln & 15, quad = ln >> 4;
  s8v* ls = (s8v*)lds;

  // ---- leader election + xcd-map publication (once) ----
  unsigned xcd;
  asm volatile("s_getreg_b32 %0, hwreg(HW_REG_XCC_ID)" : "=s"(xcd));
  xcd &= 7;
  if (tid == 0) {
    unsigned exp = 0xFFFFFFFFu;
    __hip_atomic_compare_exchange_strong(g.lead + xcd * 16, &exp, (unsigned)blk,
        __ATOMIC_ACQ_REL, __ATOMIC_RELAXED, __HIP_MEMORY_SCOPE_AGENT);
    astore(g.bxcd + blk * 16, xcd);
    // release: bxcd + CAS globally visible before arrive=1 is observed
    __hip_atomic_store(g.arrive + blk * 16, 1u, __ATOMIC_RELEASE,
                       __HIP_MEMORY_SCOPE_AGENT);
  }

  // ---- stage this block's static weight slice into LDS (overlaps election) ----
  if (blk < 64) {
    const int hg = blk;
#pragma unroll
    for (int gi = 0; gi < 3; ++gi) {
      const s8v* src = (const s8v*)((const short*)g.Whh0 + (size_t)(gi * 64 + hg) * 16384);
      for (int i = tid; i < 2048; i += 512) ls[gi * 2048 + i] = src[i];
    }
  } else if (blk < 192) {
    const int ng = (blk - 64) & 63;
#pragma unroll
    for (int gi = 0; gi < 3; ++gi) {
      const s8v* src = (const s8v*)((const short*)g.Wih1 + (size_t)(gi * 64 + ng) * 16384);
      for (int i = tid; i < 2048; i += 512) ls[gi * 2048 + i] = src[i];
    }
  } else if (blk < 208) {
    const int og = blk - 192;
#pragma unroll
    for (int u = 0; u < 2; ++u) {
      const s8v* src = (const s8v*)((const short*)g.Wof + (size_t)(og * 2 + u) * 16384);
      for (int i = tid; i < 2048; i += 512) ls[u * 2048 + i] = src[i];
    }
  }

  // ---- init handshake: all blocks resident & elections done ----
  if (tid < NBLK) {
    while (aload(g.arrive + tid * 16) < 1u) __builtin_amdgcn_s_sleep(1);
  }
  __syncthreads();
  if (tid == 0) {
    unsigned am = 0;
    for (int x = 0; x < NXCD; ++x)
      if (aload(g.lead + x * 16) != 0xFFFFFFFFu) am |= (1u << x);
    sb_amask = am;
    sb_lead = (aload(g.lead + xcd * 16) == (unsigned)blk) ? (int)xcd : -1;
  }
  __syncthreads();
  const int mylead = sb_lead;
  const unsigned amask = sb_amask;
  const bool mine = (tid < NBLK) && (aload(g.bxcd + tid * 16) == xcd);
  unsigned* goflag = g.go + xcd * 16;

  const f4v z4 = {0.f, 0.f, 0.f, 0.f};

  if (blk < 64) {
    // ================= L0: t = k =================
    const int hg = blk;
    const int MT0 = w * 2;
    const int n = hg * 16 + l15;
    const float bhn = g.bhh0n[n];
    const int kc2 = hg >> 1;
    const int lhigh = ((hg & 1) << 1) + (l15 >> 3);
    const int jp = l15 & 7;
    const int aoff = MT0 * 16384 + ln * 8;
    for (int k = 0; k <= TLEN + 2; ++k) {
      if (k <= 255) {
        const short* h0f_in = (const short*)((k & 1) ? g.H0f1 : g.H0f0);
        short* h0f_out = (short*)((k & 1) ? g.H0f0 : g.H0f1);
        const float* h0l_in = (k & 1) ? g.H0l1 : g.H0l0;
        float* h0l_out = (k & 1) ? g.H0l0 : g.H0l1;
        float tr_[2][4], tz_[2][4], tn_[2][4], hp[2][4];
#pragma unroll
        for (int mi = 0; mi < 2; ++mi)
#pragma unroll
          for (int r = 0; r < 4; ++r) {
            const int m = ((MT0 + mi) << 4) + (quad << 2) + r;
            const int tok = k ? g.target[m * TLEN + k - 1] : 0;
            const float* trow = g.table + (size_t)tok * H3;
            tr_[mi][r] = trow[n];
            tz_[mi][r] = trow[n + 1024];
            tn_[mi][r] = trow[n + 2048];
            hp[mi][r] = h0l_in[(size_t)m * HDIM + n];
          }
        f4v a0[2] = {z4, z4}, a1[2] = {z4, z4}, a2[2] = {z4, z4};
        const short* pA = h0f_in + aoff;
#pragma unroll 4
        for (int kc = 0; kc < 32; ++kc) {
          s8v A0 = ld8(pA + kc * 512);
          s8v A1 = ld8(pA + 16384 + kc * 512);
          s8v B0 = ls[kc * 64 + ln];
          s8v B1 = ls[2048 + kc * 64 + ln];
          s8v B2 = ls[4096 + kc * 64 + ln];
          a0[0] = mfma_bf16(A0, B0, a0[0]); a0[1] = mfma_bf16(A1, B0, a0[1]);
          a1[0] = mfma_bf16(A0, B1, a1[0]); a1[1] = mfma_bf16(A1, B1, a1[1]);
          a2[0] = mfma_bf16(A0, B2, a2[0]); a2[1] = mfma_bf16(A1, B2, a2[1]);
        }
#pragma unroll
        for (int mi = 0; mi < 2; ++mi) {
          const int MT = MT0 + mi;
          short* fo = h0f_out + (((size_t)(MT * 32 + kc2)) << 9) + jp;
#pragma unroll
          for (int r = 0; r < 4; ++r) {
            const int m = (MT << 4) + (quad << 2) + r;
            float rr = sigf(tr_[mi][r] + a0[mi][r]);
            float zz = sigf(tz_[mi][r] + a1[mi][r]);
            float nn = tanhf(tn_[mi][r] + rr * (a2[mi][r] + bhn));
            float hv = (1.f - zz) * nn + zz * hp[mi][r];
            h0l_out[(size_t)m * HDIM + n] = hv;
            fo[((quad << 2) + r + (lhigh << 4)) * 8] = f2bs(hv);
          }
        }
      }
      if (k < TLEN + 2) gridbar(g.arrive, g.done, goflag, (unsigned)k + 2u,
                                mylead, amask, mine, tid, blk);
    }
  } else if (blk < 192) {
    // ================= L1: t = k-1 =================
    const int b1 = blk - 64;
    const int ng = b1 & 63, mg = b1 >> 6;
    const int MT = mg * 8 + w;
    const int n = ng * 16 + l15;
    const float br = g.bih1[n] + g.bhh1[n];
    const float bz = g.bih1[n + 1024] + g.bhh1[n + 1024];
    const float bin = g.bih1[n + 2048], bhn = g.bhh1[n + 2048];
    const int kc2 = ng >> 1;
    const int lhigh = ((ng & 1) << 1) + (l15 >> 3);
    const int jp = l15 & 7;
    const int aoff = MT * 16384 + ln * 8;
    const short* pH0 = (const short*)g.Whh1 + (size_t)(ng) * 16384 + ln * 8;
    const short* pH1 = (const short*)g.Whh1 + (size_t)(64 + ng) * 16384 + ln * 8;
    const short* pH2 = (const short*)g.Whh1 + (size_t)(128 + ng) * 16384 + ln * 8;
    for (int k = 0; k <= TLEN + 2; ++k) {
      if (k >= 1 && k <= 256) {
        const short* h0f_in = (const short*)((k & 1) ? g.H0f1 : g.H0f0);     // H0[k-1]
        const short* h1f_in = (const short*)((k & 1) ? g.H1f0 : g.H1f1);     // H1[k-2]
        short* h1f_out = (short*)((k & 1) ? g.H1f1 : g.H1f0);
        const float* h1l_in = (k & 1) ? g.H1l0 : g.H1l1;
        float* h1l_out = (k & 1) ? g.H1l1 : g.H1l0;
        float hp[4];
#pragma unroll
        for (int r = 0; r < 4; ++r)
          hp[r] = h1l_in[(size_t)((MT << 4) + (quad << 2) + r) * HDIM + n];
        f4v ar = z4, az = z4, ain = z4, ahn = z4;
        const short* pAx = h0f_in + aoff;
        const short* pAh = h1f_in + aoff;
#pragma unroll 4
        for (int kc = 0; kc < 32; ++kc) {
          s8v Ax = ld8(pAx + kc * 512);
          s8v Ah = ld8(pAh + kc * 512);
          s8v Bir = ls[kc * 64 + ln];
          s8v Biz = ls[2048 + kc * 64 + ln];
          s8v Bin = ls[4096 + kc * 64 + ln];
          s8v Bhr = ld8(pH0 + kc * 512);
          s8v Bhz = ld8(pH1 + kc * 512);
          s8v Bhn = ld8(pH2 + kc * 512);
          ar = mfma_bf16(Ax, Bir, ar); ar = mfma_bf16(Ah, Bhr, ar);
          az = mfma_bf16(Ax, Biz, az); az = mfma_bf16(Ah, Bhz, az);
          ain = mfma_bf16(Ax, Bin, ain);
          ahn = mfma_bf16(Ah, Bhn, ahn);
        }
        short* fo = h1f_out + (((size_t)(MT * 32 + kc2)) << 9) + jp;
#pragma unroll
        for (int r = 0; r < 4; ++r) {
          const int m = (MT << 4) + (quad << 2) + r;
          float rr = sigf(ar[r] + br);
          float zz = sigf(az[r] + bz);
          float nn = tanhf(ain[r] + bin + rr * (ahn[r] + bhn));
          float hv = (1.f - zz) * nn + zz * hp[r];
          h1l_out[(size_t)m * HDIM + n] = hv;
          fo[((quad << 2) + r + (lhigh << 4)) * 8] = f2bs(hv);
        }
      }
      if (k < TLEN + 2) gridbar(g.arrive, g.done, goflag, (unsigned)k + 2u,
                                mylead, amask, mine, tid, blk);
    }
  } else if (blk < 208) {
    // ================= OPG: logits, t = k-2 =================
    const int og = blk - 192;
    const int MT0 = w * 2;
    float bov[2];
    bov[0] = g.bo[og * 32 + l15];
    bov[1] = g.bo[og * 32 + 16 + l15];
    const int aoff = MT0 * 16384 + ln * 8;
    for (int k = 0; k <= TLEN + 2; ++k) {
      if (k >= 2 && k <= 257) {
        const short* h1f_in = (const short*)((k & 1) ? g.H1f0 : g.H1f1);     // H1[k-1]
        float* LG = (k & 1) ? g.LG1 : g.LG0;
        f4v acc[2][2] = {{z4, z4}, {z4, z4}};
        const short* pA = h1f_in + aoff;
#pragma unroll 4
        for (int kc = 0; kc < 32; ++kc) {
          s8v A0 = ld8(pA + kc * 512);
          s8v A1 = ld8(pA + 16384 + kc * 512);
          s8v B0 = ls[kc * 64 + ln];
          s8v B1 = ls[2048 + kc * 64 + ln];
          acc[0][0] = mfma_bf16(A0, B0, acc[0][0]);
          acc[0][1] = mfma_bf16(A0, B1, acc[0][1]);
          acc[1][0] = mfma_bf16(A1, B0, acc[1][0]);
          acc[1][1] = mfma_bf16(A1, B1, acc[1][1]);
        }
#pragma unroll
        for (int mi = 0; mi < 2; ++mi)
#pragma unroll
          for (int u = 0; u < 2; ++u)
#pragma unroll
            for (int r = 0; r < 4; ++r) {
              const int m = ((MT0 + mi) << 4) + (quad << 2) + r;
              LG[((size_t)m << 9) + og * 32 + (u << 4) + l15] = acc[mi][u][r] + bov[u];
            }
      }
      if (k < TLEN + 2) gridbar(g.arrive, g.done, goflag, (unsigned)k + 2u,
                                mylead, amask, mine, tid, blk);
    }
  } else {
    // ================= OPS: log-softmax, t = k-3 =================
    const int ob = blk - 208;
    const int row = ob * 32 + (tid >> 4);
    const int l16 = tid & 15;
    for (int k = 0; k <= TLEN + 2; ++k) {
      if (k >= 3) {
        const int t = k - 3;
        const float* lr = ((k & 1) ? g.LG0 : g.LG1) + ((size_t)row << 9);
        float v[32];
        float mx = -1e30f;
#pragma unroll
        for (int j = 0; j < 32; ++j) { v[j] = lr[l16 + (j << 4)]; mx = fmaxf(mx, v[j]); }
#pragma unroll
        for (int o = 8; o > 0; o >>= 1) mx = fmaxf(mx, __shfl_xor(mx, o));
        float sum = 0.f;
#pragma unroll
        for (int j = 0; j < 32; ++j) sum += expf(v[j] - mx);
#pragma unroll
        for (int o = 8; o > 0; o >>= 1) sum += __shfl_xor(sum, o);
        const float lse = mx + logf(sum);
        float* orow = g.out + ((size_t)row * TLEN + t) * VDIM;
#pragma unroll
        for (int j = 0; j < 32; ++j) orow[l16 + (j << 4)] = v[j] - lse;
      }
      if (k < TLEN + 2) gridbar(g.arrive, g.done, goflag, (unsigned)k + 2u,
                                mylead, amask, mine, tid, blk);
    }
  }
}

// ============ final: h_final [2,B,H] (natural layout -> plain concat copy) ============
__global__ __launch_bounds__(256) void unperm_hfinal(const float* __restrict__ h0l,
                                                     const float* __restrict__ h1l,
                                                     float* __restrict__ out) {
  int idx = blockIdx.x * 256 + threadIdx.x;   // 2*B*H
  const int BH = BATCH * HDIM;
  out[idx] = (idx < BH) ? h0l[idx] : h1l[idx - BH];
}

extern "C" void kernel_launch(void* const* d_in, const int* in_sizes, int n_in,
                              void* d_out, int out_size, void* d_ws, size_t ws_size,
                              hipStream_t stream) {
  const float* fps    = (const float*)d_in[1];
  const int* target   = (const int*)d_in[2];
  const float* emb    = (const float*)d_in[3];
  const float* Wc     = (const float*)d_in[4];
  const float* bc     = (const float*)d_in[5];
  const float* W_ih   = (const float*)d_in[6];   // [2,3H,H]
  const float* W_hh   = (const float*)d_in[7];
  const float* b_ih   = (const float*)d_in[8];
  const float* b_hh   = (const float*)d_in[9];
  const float* Wo     = (const float*)d_in[10];
  const float* bo     = (const float*)d_in[11];
  float* out = (float*)d_out;

  const int BH = BATCH * HDIM;
  const size_t WN = (size_t)H3 * HDIM;

  char* p = (char*)d_ws;
  float* hstd  = (float*)p; p += (size_t)BH * 4;
  float* table = (float*)p; p += (size_t)VDIM * H3 * 4;
  float* H0l[2]; H0l[0] = (float*)p; p += (size_t)BH * 4; H0l[1] = (float*)p; p += (size_t)BH * 4;
  float* H1l[2]; H1l[0] = (float*)p; p += (size_t)BH * 4; H1l[1] = (float*)p; p += (size_t)BH * 4;
  bf16* H0f[2]; H0f[0] = (bf16*)p; p += (size_t)BH * 2; H0f[1] = (bf16*)p; p += (size_t)BH * 2;
  bf16* H1f[2]; H1f[0] = (bf16*)p; p += (size_t)BH * 2; H1f[1] = (bf16*)p; p += (size_t)BH * 2;
  bf16* Whh0f = (bf16*)p; p += WN * 2;
  bf16* Wih1f = (bf16*)p; p += WN * 2;
  bf16* Whh1f = (bf16*)p; p += WN * 2;
  bf16* Wof   = (bf16*)p; p += (size_t)VDIM * HDIM * 2;
  float* LG0  = (float*)p; p += (size_t)BATCH * VDIM * 4;
  float* LG1  = (float*)p; p += (size_t)BATCH * VDIM * 4;
  unsigned* arrive = (unsigned*)p; p += (size_t)NBLK * 64;
  unsigned* done   = (unsigned*)p; p += (size_t)NXCD * 64;
  unsigned* lead   = (unsigned*)p; p += (size_t)NXCD * 64;
  unsigned* go     = (unsigned*)p; p += (size_t)NXCD * 64;
  unsigned* bxcd   = (unsigned*)p; p += (size_t)NBLK * 64;

  static bool attr_done = false;
  if (!attr_done) {
    hipFuncSetAttribute(reinterpret_cast<const void*>(step_persist),
                        hipFuncAttributeMaxDynamicSharedMemorySize, 96 * 1024);
    attr_done = true;
  }

  hipMemsetAsync(arrive, 0, (size_t)NBLK * 64, stream);
  hipMemsetAsync(done, 0, (size_t)NXCD * 64, stream);
  hipMemsetAsync(lead, 0xFF, (size_t)NXCD * 64, stream);
  hipMemsetAsync(go, 0, (size_t)NXCD * 64, stream);
  hipMemsetAsync(bxcd, 0, (size_t)NBLK * 64, stream);

  // one-time weight shuffles into fragment blobs
  {
    int ng3 = (H3 / 16) * 32 * 64;             // 393216
    shuffle_w<<<ng3 / 256, 256, 0, stream>>>(W_hh, Whh0f, ng3);
    shuffle_w<<<ng3 / 256, 256, 0, stream>>>(W_ih + WN, Wih1f, ng3);
    shuffle_w<<<ng3 / 256, 256, 0, stream>>>(W_hh + WN, Whh1f, ng3);
    int ngv = (VDIM / 16) * 32 * 64;           // 65536
    shuffle_w<<<ngv / 256, 256, 0, stream>>>(Wo, Wof, ngv);
  }
  // init hidden: hstd = relu(fps @ Wc^T + bc)
  {
    GemmArgs a; a.A = fps; a.W = Wc; a.bias = bc; a.bias2 = nullptr;
    a.C = hstd; a.ldc = HDIM; a.K = FPDIM; a.reluA = 0; a.reluC = 1; a.b2lim = 0;
    gemm_bt<<<dim3(HDIM / 64, BATCH / 64), 256, 0, stream>>>(a);
  }
  // gi0 table = relu(emb) @ Wih0^T + b_ih0 + b_hh0 (r,z parts only)
  {
    GemmArgs a; a.A = emb; a.W = W_ih; a.bias = b_ih; a.bias2 = b_hh;
    a.C = table; a.ldc = H3; a.K = HDIM; a.reluA = 1; a.reluC = 0; a.b2lim = 2048;
    gemm_bt<<<dim3(H3 / 64, VDIM / 64), 256, 0, stream>>>(a);
  }
  // init hidden into fp32 state (natural layout) + frag blobs (parity-0 buffers)
  copy2<<<BH / 256, 256, 0, stream>>>(hstd, H0l[0], H1l[0]);
  permute_frag<<<(BATCH / 16) * 32 * 64 / 256, 256, 0, stream>>>(hstd, H0f[0], H1f[0]);

  // the persistent decoder
  PArgs pa;
  pa.target = target; pa.table = table; pa.bhh0n = b_hh + 2048;
  pa.bih1 = b_ih + H3; pa.bhh1 = b_hh + H3; pa.bo = bo;
  pa.Whh1 = Whh1f;
  pa.H0f0 = H0f[0]; pa.H0f1 = H0f[1]; pa.H1f0 = H1f[0]; pa.H1f1 = H1f[1];
  pa.H0l0 = H0l[0]; pa.H0l1 = H0l[1]; pa.H1l0 = H1l[0]; pa.H1l1 = H1l[1];
  pa.LG0 = LG0; pa.LG1 = LG1;
  pa.out = out;
  pa.arrive = arrive; pa.done = done; pa.lead = lead; pa.go = go; pa.bxcd = bxcd;
  pa.Whh0 = Whh0f; pa.Wih1 = Wih1f; pa.Wof = Wof;
  step_persist<<<NBLK, 512, 96 * 1024, stream>>>(pa);

  // h_final = [H0[256], H1[256]] (both land in parity-0 buffers)
  unperm_hfinal<<<2 * BH / 256, 256, 0, stream>>>(H0l[0], H1l[0],
                                                  out + (size_t)BATCH * TLEN * VDIM);
}

// Round 6
// 7467.970 us; speedup vs baseline: 3.8730x; 1.0531x over previous
//
#include <hip/hip_runtime.h>
#include <hip/hip_bf16.h>

#define HDIM 1024
#define VDIM 512
#define TLEN 256
#define BATCH 256
#define FPDIM 2048
#define H3 3072
#define NBLK 216
#define NXCD 8

typedef __hip_bfloat16 bf16;
typedef unsigned long long u64t;
typedef __attribute__((ext_vector_type(8))) short s8v;    // 8 bf16 (4 VGPRs)
typedef __attribute__((ext_vector_type(4))) float f4v;    // MFMA C/D

__device__ __forceinline__ f4v mfma_bf16(s8v a, s8v b, f4v c) {
  return __builtin_amdgcn_mfma_f32_16x16x32_bf16(a, b, c, 0, 0, 0);
}
__device__ __forceinline__ s8v ld8(const short* p) { return *(const s8v*)p; }
__device__ __forceinline__ float sigf(float x) { return 1.f / (1.f + expf(-x)); }
// fp32 -> bf16 bits, RNE
__device__ __forceinline__ short f2bs(float f) {
  union { float f; unsigned u; } c; c.f = f;
  unsigned u = c.u + 0x7fff + ((c.u >> 16) & 1);
  return (short)(u >> 16);
}

// ---- agent-coherent (L2-bypassing, fence-free) access helpers ----
__device__ __forceinline__ unsigned aload(const unsigned* p) {
  return __hip_atomic_load(p, __ATOMIC_RELAXED, __HIP_MEMORY_SCOPE_AGENT);
}
__device__ __forceinline__ void astore(unsigned* p, unsigned v) {
  __hip_atomic_store(p, v, __ATOMIC_RELAXED, __HIP_MEMORY_SCOPE_AGENT);
}
__device__ __forceinline__ s8v ld8c(const short* p) {      // 16B frag, coherent
  union { u64t q[2]; s8v v; } u;
  u.q[0] = __hip_atomic_load((const u64t*)p, __ATOMIC_RELAXED, __HIP_MEMORY_SCOPE_AGENT);
  u.q[1] = __hip_atomic_load((const u64t*)p + 1, __ATOMIC_RELAXED, __HIP_MEMORY_SCOPE_AGENT);
  return u.v;
}
__device__ __forceinline__ void stsc(short* p, short v) {  // 2B frag store, coherent
  __hip_atomic_store(p, v, __ATOMIC_RELAXED, __HIP_MEMORY_SCOPE_AGENT);
}
__device__ __forceinline__ void stfc(float* p, float v) {
  __hip_atomic_store(p, v, __ATOMIC_RELAXED, __HIP_MEMORY_SCOPE_AGENT);
}
__device__ __forceinline__ float ldfc(const float* p) {
  return __hip_atomic_load(p, __ATOMIC_RELAXED, __HIP_MEMORY_SCOPE_AGENT);
}

// ============ one-time: fp32 [N,1024] -> bf16 MFMA-frag blob ============
// blob[((nt*32+kc)*64 + lane)*8 + j]; n = nt*16+(lane&15), k = kc*32+(lane>>4)*8+j
__global__ __launch_bounds__(256) void shuffle_w(const float* __restrict__ src,
                                                 bf16* __restrict__ dst, int ngroups) {
  int g = blockIdx.x * 256 + threadIdx.x;
  if (g >= ngroups) return;
  int lane = g & 63, kc = (g >> 6) & 31, nt = g >> 11;
  int n = nt * 16 + (lane & 15);
  int k = kc * 32 + ((lane >> 4) << 3);
  const float* s = src + (size_t)n * HDIM + k;
  short* d = (short*)dst + (size_t)g * 8;
  s8v v;
#pragma unroll
  for (int j = 0; j < 8; ++j) v[j] = f2bs(s[j]);
  *(s8v*)d = v;
}

// ============ one-time fp32 tile GEMM: C = [relu](A[M,K] @ W[N,K]^T + bias [+bias2 if n<lim]) ============
struct GemmArgs {
  const float* A; const float* W; const float* bias; const float* bias2;
  float* C; int ldc; int K; int reluA; int reluC; int b2lim;
};
#define LDP 68
__global__ __launch_bounds__(256) void gemm_bt(GemmArgs g) {
  __shared__ float As[16][LDP];
  __shared__ float Ws[16][LDP];
  const int tid = threadIdx.x;
  const int tx = tid & 15, ty = tid >> 4;
  const int m0 = blockIdx.y * 64, n0 = blockIdx.x * 64;
  float acc[4][4] = {{0.f, 0.f, 0.f, 0.f}};
  const int K = g.K;
  for (int kb = 0; kb < K / 16; ++kb) {
    const int k0 = kb * 16;
#pragma unroll
    for (int i = 0; i < 4; ++i) {
      int idx = tid + i * 256;
      int ml = idx >> 4, kl = idx & 15;
      float a = g.A[(size_t)(m0 + ml) * K + k0 + kl];
      if (g.reluA) a = fmaxf(a, 0.f);
      As[kl][ml] = a;
      Ws[kl][ml] = g.W[(size_t)(n0 + ml) * K + k0 + kl];
    }
    __syncthreads();
#pragma unroll
    for (int k = 0; k < 16; ++k) {
      float4 av = *(const float4*)&As[k][ty * 4];
      float4 wv = *(const float4*)&Ws[k][tx * 4];
      float a[4] = {av.x, av.y, av.z, av.w};
      float w[4] = {wv.x, wv.y, wv.z, wv.w};
#pragma unroll
      for (int i = 0; i < 4; ++i)
#pragma unroll
        for (int j = 0; j < 4; ++j)
          acc[i][j] = fmaf(a[i], w[j], acc[i][j]);
    }
    __syncthreads();
  }
#pragma unroll
  for (int i = 0; i < 4; ++i) {
    int m = m0 + ty * 4 + i;
#pragma unroll
    for (int j = 0; j < 4; ++j) {
      int n = n0 + tx * 4 + j;
      float v = acc[i][j] + g.bias[n];
      if (g.bias2 && n < g.b2lim) v += g.bias2[n];
      if (g.reluC) v = fmaxf(v, 0.f);
      g.C[(size_t)m * g.ldc + n] = v;
    }
  }
}

// ============ one-time: duplicate init hidden into both layers' fp32 state bufs ============
__global__ __launch_bounds__(256) void copy2(const float* __restrict__ s,
                                             float* __restrict__ d0,
                                             float* __restrict__ d1) {
  int i = blockIdx.x * 256 + threadIdx.x;
  float v = s[i];
  d0[i] = v; d1[i] = v;
}

// init hidden -> frag blobs (both layers)
__global__ __launch_bounds__(256) void permute_frag(const float* __restrict__ s,
                                                    bf16* __restrict__ d0,
                                                    bf16* __restrict__ d1) {
  int g = blockIdx.x * 256 + threadIdx.x;      // (B/16)*32*64 groups
  int lane = g & 63, kc = (g >> 6) & 31, mt = g >> 11;
  int m = mt * 16 + (lane & 15), k = kc * 32 + ((lane >> 4) << 3);
  const float* src = s + (size_t)m * HDIM + k;
  s8v v;
#pragma unroll
  for (int j = 0; j < 8; ++j) v[j] = f2bs(src[j]);
  *(s8v*)((short*)d0 + (size_t)g * 8) = v;
  *(s8v*)((short*)d1 + (size_t)g * 8) = v;
}

// ============ persistent fused decoder ============
// ONE kernel for all 256 steps. 216 blocks x 512 thr, 1 block/CU (96 KB LDS).
// Roles: blk 0..63 L0 | 64..191 L1 | 192..207 OPG | 208..215 OPS.
// Coherence v4: NO cache fences anywhere in the loop (a single buffer_wbl2 is a
// ~13us full-L2 tag walk -- the R4/R5 floor).  Cross-XCD data (frag blobs, LG)
// uses agent-scope relaxed atomics (sc1: L2-bypass, L3-coherent per access).
// Block-private state (h0l/h1l) and read-only weights stay L2-cached; streamed
// Whh1 is now L2-resident across all steps (no inv ever runs).
// Barrier v4: arrive flags -> per-XCD leader -> done[xcd]; all blocks poll the
// 8 done flags.  Two L3 hops, zero cache ops.
struct PArgs {
  const int* target;
  const float* table;          // [V,3H] fp32
  const float* bhh0n;          // b_hh0 + 2048
  const float* bih1; const float* bhh1; const float* bo;
  const bf16* Whh1;            // L1 h-src weight blob (streamed, L2-resident)
  bf16 *H0f0, *H0f1, *H1f0, *H1f1;
  float *H0l0, *H0l1, *H1l0, *H1l1;
  float *LG0, *LG1;            // logits double buffer [256][512] f32
  float* out;
  unsigned* arrive;            // [NBLK] padded x16 (64B lines)
  unsigned* done;              // [NXCD] padded x16
  unsigned* lead;              // [NXCD] padded x16, leader block id or ~0u
  unsigned* bxcd;              // [NBLK] padded x16, block -> xcd map
  const bf16 *Whh0, *Wih1, *Wof;   // blobs for LDS staging
};

__device__ __forceinline__ void gridbar(unsigned* arrive, unsigned* done,
                                        unsigned gen, int mylead, unsigned amask,
                                        bool mine, int tid, int blk) {
  __syncthreads();   // vmcnt(0): all sc1 data stores are at L3 (globally visible)
  if (tid == 0) astore(arrive + blk * 16, gen);
  if (mylead >= 0) {                     // this block is leader of XCD 'mylead'
    if (mine) {                          // mine => tid<NBLK and bxcd[tid]==my xcd
      while (aload(arrive + tid * 16) < gen) __builtin_amdgcn_s_sleep(1);
    }
    __syncthreads();                     // own-XCD arrivals confirmed
    if (tid == 0) astore(done + mylead * 16, gen);
  }
  if (tid < NXCD && ((amask >> tid) & 1u)) {
    while (aload(done + tid * 16) < gen) __builtin_amdgcn_s_sleep(1);
  }
  __syncthreads();
}

__global__ __launch_bounds__(512, 2) void step_persist(PArgs g) {
  extern __shared__ short lds[];               // 96 KB dynamic
  __shared__ int sb_lead;
  __shared__ unsigned sb_amask;
  const int blk = blockIdx.x, tid = threadIdx.x;
  const int w = tid >> 6, ln = tid & 63, l15 = ln & 15, quad = ln >> 4;
  s8v* ls = (s8v*)lds;

  // ---- leader election + xcd-map publication (once) ----
  unsigned xcd;
  asm volatile("s_getreg_b32 %0, hwreg(HW_REG_XCC_ID)" : "=s"(xcd));
  xcd &= 7;
  if (tid == 0) {
    unsigned exp = 0xFFFFFFFFu;
    __hip_atomic_compare_exchange_strong(g.lead + xcd * 16, &exp, (unsigned)blk,
        __ATOMIC_ACQ_REL, __ATOMIC_RELAXED, __HIP_MEMORY_SCOPE_AGENT);
    astore(g.bxcd + blk * 16, xcd);
    // release: bxcd + CAS globally visible before arrive=1 is observed (one-time)
    __hip_atomic_store(g.arrive + blk * 16, 1u, __ATOMIC_RELEASE,
                       __HIP_MEMORY_SCOPE_AGENT);
  }

  // ---- stage this block's static weight slice into LDS (overlaps election) ----
  if (blk < 64) {
    const int hg = blk;
#pragma unroll
    for (int gi = 0; gi < 3; ++gi) {
      const s8v* src = (const s8v*)((const short*)g.Whh0 + (size_t)(gi * 64 + hg) * 16384);
      for (int i = tid; i < 2048; i += 512) ls[gi * 2048 + i] = src[i];
    }
  } else if (blk < 192) {
    const int ng = (blk - 64) & 63;
#pragma unroll
    for (int gi = 0; gi < 3; ++gi) {
      const s8v* src = (const s8v*)((const short*)g.Wih1 + (size_t)(gi * 64 + ng) * 16384);
      for (int i = tid; i < 2048; i += 512) ls[gi * 2048 + i] = src[i];
    }
  } else if (blk < 208) {
    const int og = blk - 192;
#pragma unroll
    for (int u = 0; u < 2; ++u) {
      const s8v* src = (const s8v*)((const short*)g.Wof + (size_t)(og * 2 + u) * 16384);
      for (int i = tid; i < 2048; i += 512) ls[u * 2048 + i] = src[i];
    }
  }

  // ---- init handshake: all blocks resident & elections done ----
  if (tid < NBLK) {
    while (aload(g.arrive + tid * 16) < 1u) __builtin_amdgcn_s_sleep(1);
  }
  __syncthreads();
  if (tid == 0) {
    unsigned am = 0;
    for (int x = 0; x < NXCD; ++x)
      if (aload(g.lead + x * 16) != 0xFFFFFFFFu) am |= (1u << x);
    sb_amask = am;
    sb_lead = (aload(g.lead + xcd * 16) == (unsigned)blk) ? (int)xcd : -1;
  }
  __syncthreads();
  const int mylead = sb_lead;
  const unsigned amask = sb_amask;
  const bool mine = (tid < NBLK) && (aload(g.bxcd + tid * 16) == xcd);

  const f4v z4 = {0.f, 0.f, 0.f, 0.f};

  if (blk < 64) {
    // ================= L0: t = k =================
    const int hg = blk;
    const int MT0 = w * 2;
    const int n = hg * 16 + l15;
    const float bhn = g.bhh0n[n];
    const int kc2 = hg >> 1;
    const int lhigh = ((hg & 1) << 1) + (l15 >> 3);
    const int jp = l15 & 7;
    const int aoff = MT0 * 16384 + ln * 8;
    for (int k = 0; k <= TLEN + 2; ++k) {
      if (k <= 255) {
        const short* h0f_in = (const short*)((k & 1) ? g.H0f1 : g.H0f0);
        short* h0f_out = (short*)((k & 1) ? g.H0f0 : g.H0f1);
        const float* h0l_in = (k & 1) ? g.H0l1 : g.H0l0;
        float* h0l_out = (k & 1) ? g.H0l0 : g.H0l1;
        float tr_[2][4], tz_[2][4], tn_[2][4], hp[2][4];
#pragma unroll
        for (int mi = 0; mi < 2; ++mi)
#pragma unroll
          for (int r = 0; r < 4; ++r) {
            const int m = ((MT0 + mi) << 4) + (quad << 2) + r;
            const int tok = k ? g.target[m * TLEN + k - 1] : 0;
            const float* trow = g.table + (size_t)tok * H3;
            tr_[mi][r] = trow[n];
            tz_[mi][r] = trow[n + 1024];
            tn_[mi][r] = trow[n + 2048];
            hp[mi][r] = h0l_in[(size_t)m * HDIM + n];
          }
        f4v a0[2] = {z4, z4}, a1[2] = {z4, z4}, a2[2] = {z4, z4};
        const short* pA = h0f_in + aoff;
#pragma unroll 4
        for (int kc = 0; kc < 32; ++kc) {
          s8v A0 = ld8c(pA + kc * 512);
          s8v A1 = ld8c(pA + 16384 + kc * 512);
          s8v B0 = ls[kc * 64 + ln];
          s8v B1 = ls[2048 + kc * 64 + ln];
          s8v B2 = ls[4096 + kc * 64 + ln];
          a0[0] = mfma_bf16(A0, B0, a0[0]); a0[1] = mfma_bf16(A1, B0, a0[1]);
          a1[0] = mfma_bf16(A0, B1, a1[0]); a1[1] = mfma_bf16(A1, B1, a1[1]);
          a2[0] = mfma_bf16(A0, B2, a2[0]); a2[1] = mfma_bf16(A1, B2, a2[1]);
        }
#pragma unroll
        for (int mi = 0; mi < 2; ++mi) {
          const int MT = MT0 + mi;
          short* fo = h0f_out + (((size_t)(MT * 32 + kc2)) << 9) + jp;
#pragma unroll
          for (int r = 0; r < 4; ++r) {
            const int m = (MT << 4) + (quad << 2) + r;
            float rr = sigf(tr_[mi][r] + a0[mi][r]);
            float zz = sigf(tz_[mi][r] + a1[mi][r]);
            float nn = tanhf(tn_[mi][r] + rr * (a2[mi][r] + bhn));
            float hv = (1.f - zz) * nn + zz * hp[mi][r];
            h0l_out[(size_t)m * HDIM + n] = hv;
            stsc(fo + ((quad << 2) + r + (lhigh << 4)) * 8, f2bs(hv));
          }
        }
      }
      if (k < TLEN + 2) gridbar(g.arrive, g.done, (unsigned)k + 2u,
                                mylead, amask, mine, tid, blk);
    }
  } else if (blk < 192) {
    // ================= L1: t = k-1 =================
    const int b1 = blk - 64;
    const int ng = b1 & 63, mg = b1 >> 6;
    const int MT = mg * 8 + w;
    const int n = ng * 16 + l15;
    const float br = g.bih1[n] + g.bhh1[n];
    const float bz = g.bih1[n + 1024] + g.bhh1[n + 1024];
    const float bin = g.bih1[n + 2048], bhn = g.bhh1[n + 2048];
    const int kc2 = ng >> 1;
    const int lhigh = ((ng & 1) << 1) + (l15 >> 3);
    const int jp = l15 & 7;
    const int aoff = MT * 16384 + ln * 8;
    const short* pH0 = (const short*)g.Whh1 + (size_t)(ng) * 16384 + ln * 8;
    const short* pH1 = (const short*)g.Whh1 + (size_t)(64 + ng) * 16384 + ln * 8;
    const short* pH2 = (const short*)g.Whh1 + (size_t)(128 + ng) * 16384 + ln * 8;
    for (int k = 0; k <= TLEN + 2; ++k) {
      if (k >= 1 && k <= 256) {
        const short* h0f_in = (const short*)((k & 1) ? g.H0f1 : g.H0f0);     // H0[k-1]
        const short* h1f_in = (const short*)((k & 1) ? g.H1f0 : g.H1f1);     // H1[k-2]
        short* h1f_out = (short*)((k & 1) ? g.H1f1 : g.H1f0);
        const float* h1l_in = (k & 1) ? g.H1l0 : g.H1l1;
        float* h1l_out = (k & 1) ? g.H1l1 : g.H1l0;
        float hp[4];
#pragma unroll
        for (int r = 0; r < 4; ++r)
          hp[r] = h1l_in[(size_t)((MT << 4) + (quad << 2) + r) * HDIM + n];
        f4v ar = z4, az = z4, ain = z4, ahn = z4;
        const short* pAx = h0f_in + aoff;
        const short* pAh = h1f_in + aoff;
#pragma unroll 4
        for (int kc = 0; kc < 32; ++kc) {
          s8v Ax = ld8c(pAx + kc * 512);
          s8v Ah = ld8c(pAh + kc * 512);
          s8v Bir = ls[kc * 64 + ln];
          s8v Biz = ls[2048 + kc * 64 + ln];
          s8v Bin = ls[4096 + kc * 64 + ln];
          s8v Bhr = ld8(pH0 + kc * 512);
          s8v Bhz = ld8(pH1 + kc * 512);
          s8v Bhn = ld8(pH2 + kc * 512);
          ar = mfma_bf16(Ax, Bir, ar); ar = mfma_bf16(Ah, Bhr, ar);
          az = mfma_bf16(Ax, Biz, az); az = mfma_bf16(Ah, Bhz, az);
          ain = mfma_bf16(Ax, Bin, ain);
          ahn = mfma_bf16(Ah, Bhn, ahn);
        }
        short* fo = h1f_out + (((size_t)(MT * 32 + kc2)) << 9) + jp;
#pragma unroll
        for (int r = 0; r < 4; ++r) {
          const int m = (MT << 4) + (quad << 2) + r;
          float rr = sigf(ar[r] + br);
          float zz = sigf(az[r] + bz);
          float nn = tanhf(ain[r] + bin + rr * (ahn[r] + bhn));
          float hv = (1.f - zz) * nn + zz * hp[r];
          h1l_out[(size_t)m * HDIM + n] = hv;
          stsc(fo + ((quad << 2) + r + (lhigh << 4)) * 8, f2bs(hv));
        }
      }
      if (k < TLEN + 2) gridbar(g.arrive, g.done, (unsigned)k + 2u,
                                mylead, amask, mine, tid, blk);
    }
  } else if (blk < 208) {
    // ================= OPG: logits, t = k-2 =================
    const int og = blk - 192;
    const int MT0 = w * 2;
    float bov[2];
    bov[0] = g.bo[og * 32 + l15];
    bov[1] = g.bo[og * 32 + 16 + l15];
    const int aoff = MT0 * 16384 + ln * 8;
    for (int k = 0; k <= TLEN + 2; ++k) {
      if (k >= 2 && k <= 257) {
        const short* h1f_in = (const short*)((k & 1) ? g.H1f0 : g.H1f1);     // H1[k-1]
        float* LG = (k & 1) ? g.LG1 : g.LG0;
        f4v acc[2][2] = {{z4, z4}, {z4, z4}};
        const short* pA = h1f_in + aoff;
#pragma unroll 4
        for (int kc = 0; kc < 32; ++kc) {
          s8v A0 = ld8c(pA + kc * 512);
          s8v A1 = ld8c(pA + 16384 + kc * 512);
          s8v B0 = ls[kc * 64 + ln];
          s8v B1 = ls[2048 + kc * 64 + ln];
          acc[0][0] = mfma_bf16(A0, B0, acc[0][0]);
          acc[0][1] = mfma_bf16(A0, B1, acc[0][1]);
          acc[1][0] = mfma_bf16(A1, B0, acc[1][0]);
          acc[1][1] = mfma_bf16(A1, B1, acc[1][1]);
        }
#pragma unroll
        for (int mi = 0; mi < 2; ++mi)
#pragma unroll
          for (int u = 0; u < 2; ++u)
#pragma unroll
            for (int r = 0; r < 4; ++r) {
              const int m = ((MT0 + mi) << 4) + (quad << 2) + r;
              stfc(&LG[((size_t)m << 9) + og * 32 + (u << 4) + l15],
                   acc[mi][u][r] + bov[u]);
            }
      }
      if (k < TLEN + 2) gridbar(g.arrive, g.done, (unsigned)k + 2u,
                                mylead, amask, mine, tid, blk);
    }
  } else {
    // ================= OPS: log-softmax, t = k-3 =================
    const int ob = blk - 208;
    const int row = ob * 32 + (tid >> 4);
    const int l16 = tid & 15;
    for (int k = 0; k <= TLEN + 2; ++k) {
      if (k >= 3) {
        const int t = k - 3;
        const float* lr = ((k & 1) ? g.LG0 : g.LG1) + ((size_t)row << 9);
        float v[32];
        float mx = -1e30f;
#pragma unroll
        for (int j = 0; j < 32; ++j) { v[j] = ldfc(&lr[l16 + (j << 4)]); mx = fmaxf(mx, v[j]); }
#pragma unroll
        for (int o = 8; o > 0; o >>= 1) mx = fmaxf(mx, __shfl_xor(mx, o));
        float sum = 0.f;
#pragma unroll
        for (int j = 0; j < 32; ++j) sum += expf(v[j] - mx);
#pragma unroll
        for (int o = 8; o > 0; o >>= 1) sum += __shfl_xor(sum, o);
        const float lse = mx + logf(sum);
        float* orow = g.out + ((size_t)row * TLEN + t) * VDIM;
#pragma unroll
        for (int j = 0; j < 32; ++j) orow[l16 + (j << 4)] = v[j] - lse;
      }
      if (k < TLEN + 2) gridbar(g.arrive, g.done, (unsigned)k + 2u,
                                mylead, amask, mine, tid, blk);
    }
  }
}

// ============ final: h_final [2,B,H] (natural layout -> plain concat copy) ============
__global__ __launch_bounds__(256) void unperm_hfinal(const float* __restrict__ h0l,
                                                     const float* __restrict__ h1l,
                                                     float* __restrict__ out) {
  int idx = blockIdx.x * 256 + threadIdx.x;   // 2*B*H
  const int BH = BATCH * HDIM;
  out[idx] = (idx < BH) ? h0l[idx] : h1l[idx - BH];
}

extern "C" void kernel_launch(void* const* d_in, const int* in_sizes, int n_in,
                              void* d_out, int out_size, void* d_ws, size_t ws_size,
                              hipStream_t stream) {
  const float* fps    = (const float*)d_in[1];
  const int* target   = (const int*)d_in[2];
  const float* emb    = (const float*)d_in[3];
  const float* Wc     = (const float*)d_in[4];
  const float* bc     = (const float*)d_in[5];
  const float* W_ih   = (const float*)d_in[6];   // [2,3H,H]
  const float* W_hh   = (const float*)d_in[7];
  const float* b_ih   = (const float*)d_in[8];
  const float* b_hh   = (const float*)d_in[9];
  const float* Wo     = (const float*)d_in[10];
  const float* bo     = (const float*)d_in[11];
  float* out = (float*)d_out;

  const int BH = BATCH * HDIM;
  const size_t WN = (size_t)H3 * HDIM;

  char* p = (char*)d_ws;
  float* hstd  = (float*)p; p += (size_t)BH * 4;
  float* table = (float*)p; p += (size_t)VDIM * H3 * 4;
  float* H0l[2]; H0l[0] = (float*)p; p += (size_t)BH * 4; H0l[1] = (float*)p; p += (size_t)BH * 4;
  float* H1l[2]; H1l[0] = (float*)p; p += (size_t)BH * 4; H1l[1] = (float*)p; p += (size_t)BH * 4;
  bf16* H0f[2]; H0f[0] = (bf16*)p; p += (size_t)BH * 2; H0f[1] = (bf16*)p; p += (size_t)BH * 2;
  bf16* H1f[2]; H1f[0] = (bf16*)p; p += (size_t)BH * 2; H1f[1] = (bf16*)p; p += (size_t)BH * 2;
  bf16* Whh0f = (bf16*)p; p += WN * 2;
  bf16* Wih1f = (bf16*)p; p += WN * 2;
  bf16* Whh1f = (bf16*)p; p += WN * 2;
  bf16* Wof   = (bf16*)p; p += (size_t)VDIM * HDIM * 2;
  float* LG0  = (float*)p; p += (size_t)BATCH * VDIM * 4;
  float* LG1  = (float*)p; p += (size_t)BATCH * VDIM * 4;
  unsigned* arrive = (unsigned*)p; p += (size_t)NBLK * 64;
  unsigned* done   = (unsigned*)p; p += (size_t)NXCD * 64;
  unsigned* lead   = (unsigned*)p; p += (size_t)NXCD * 64;
  unsigned* bxcd   = (unsigned*)p; p += (size_t)NBLK * 64;

  static bool attr_done = false;
  if (!attr_done) {
    hipFuncSetAttribute(reinterpret_cast<const void*>(step_persist),
                        hipFuncAttributeMaxDynamicSharedMemorySize, 96 * 1024);
    attr_done = true;
  }

  hipMemsetAsync(arrive, 0, (size_t)NBLK * 64, stream);
  hipMemsetAsync(done, 0, (size_t)NXCD * 64, stream);
  hipMemsetAsync(lead, 0xFF, (size_t)NXCD * 64, stream);
  hipMemsetAsync(bxcd, 0, (size_t)NBLK * 64, stream);

  // one-time weight shuffles into fragment blobs
  {
    int ng3 = (H3 / 16) * 32 * 64;             // 393216
    shuffle_w<<<ng3 / 256, 256, 0, stream>>>(W_hh, Whh0f, ng3);
    shuffle_w<<<ng3 / 256, 256, 0, stream>>>(W_ih + WN, Wih1f, ng3);
    shuffle_w<<<ng3 / 256, 256, 0, stream>>>(W_hh + WN, Whh1f, ng3);
    int ngv = (VDIM / 16) * 32 * 64;           // 65536
    shuffle_w<<<ngv / 256, 256, 0, stream>>>(Wo, Wof, ngv);
  }
  // init hidden: hstd = relu(fps @ Wc^T + bc)
  {
    GemmArgs a; a.A = fps; a.W = Wc; a.bias = bc; a.bias2 = nullptr;
    a.C = hstd; a.ldc = HDIM; a.K = FPDIM; a.reluA = 0; a.reluC = 1; a.b2lim = 0;
    gemm_bt<<<dim3(HDIM / 64, BATCH / 64), 256, 0, stream>>>(a);
  }
  // gi0 table = relu(emb) @ Wih0^T + b_ih0 + b_hh0 (r,z parts only)
  {
    GemmArgs a; a.A = emb; a.W = W_ih; a.bias = b_ih; a.bias2 = b_hh;
    a.C = table; a.ldc = H3; a.K = HDIM; a.reluA = 1; a.reluC = 0; a.b2lim = 2048;
    gemm_bt<<<dim3(H3 / 64, VDIM / 64), 256, 0, stream>>>(a);
  }
  // init hidden into fp32 state (natural layout) + frag blobs (parity-0 buffers)
  copy2<<<BH / 256, 256, 0, stream>>>(hstd, H0l[0], H1l[0]);
  permute_frag<<<(BATCH / 16) * 32 * 64 / 256, 256, 0, stream>>>(hstd, H0f[0], H1f[0]);

  // the persistent decoder
  PArgs pa;
  pa.target = target; pa.table = table; pa.bhh0n = b_hh + 2048;
  pa.bih1 = b_ih + H3; pa.bhh1 = b_hh + H3; pa.bo = bo;
  pa.Whh1 = Whh1f;
  pa.H0f0 = H0f[0]; pa.H0f1 = H0f[1]; pa.H1f0 = H1f[0]; pa.H1f1 = H1f[1];
  pa.H0l0 = H0l[0]; pa.H0l1 = H0l[1]; pa.H1l0 = H1l[0]; pa.H1l1 = H1l[1];
  pa.LG0 = LG0; pa.LG1 = LG1;
  pa.out = out;
  pa.arrive = arrive; pa.done = done; pa.lead = lead; pa.bxcd = bxcd;
  pa.Whh0 = Whh0f; pa.Wih1 = Wih1f; pa.Wof = Wof;
  step_persist<<<NBLK, 512, 96 * 1024, stream>>>(pa);

  // h_final = [H0[256], H1[256]] (both land in parity-0 buffers)
  unperm_hfinal<<<2 * BH / 256, 256, 0, stream>>>(H0l[0], H1l[0],
                                                  out + (size_t)BATCH * TLEN * VDIM);
}